// Round 3
// baseline (4482.413 us; speedup 1.0000x reference)
//
#include <hip/hip_runtime.h>

typedef unsigned short ushort_t;
typedef unsigned int uint_t;

// ---------- helpers ----------
__device__ __forceinline__ float b2f(ushort_t u) {
    union { uint_t i; float f; } v; v.i = ((uint_t)u) << 16; return v.f;
}
__device__ __forceinline__ float blo(uint_t u) {
    union { uint_t i; float f; } v; v.i = u << 16; return v.f;
}
__device__ __forceinline__ float bhi(uint_t u) {
    union { uint_t i; float f; } v; v.i = u & 0xffff0000u; return v.f;
}
__device__ __forceinline__ ushort_t f2b(float f) {
    union { float f; uint_t i; } v; v.f = f;
    uint_t r = v.i + 0x7fffu + ((v.i >> 16) & 1u);
    return (ushort_t)(r >> 16);
}
__device__ __forceinline__ float gelu_exact(float x) {
    return 0.5f * x * (1.0f + erff(x * 0.70710678118654752f));
}

// ---------- LayerNorm (+ optional GELU); C = 384, 128 threads, 1 block/row ----------
__global__ __launch_bounds__(128) void ln_kernel(const float* __restrict__ in,
                                                 const float* __restrict__ w,
                                                 const float* __restrict__ b,
                                                 float* __restrict__ out, int act) {
    const int C = 384;
    int row = blockIdx.x, tid = threadIdx.x;
    size_t base = (size_t)row * C;
    float x[3], s = 0.f, s2 = 0.f;
#pragma unroll
    for (int i = 0; i < 3; i++) {
        int c = tid + i * 128;
        float v = in[base + c];
        x[i] = v; s += v; s2 += v * v;
    }
    for (int off = 32; off; off >>= 1) { s += __shfl_down(s, off); s2 += __shfl_down(s2, off); }
    __shared__ float sc[4];
    int lane = tid & 63, wid = tid >> 6;
    if (lane == 0) { sc[wid] = s; sc[wid + 2] = s2; }
    __syncthreads();
    float ts = sc[0] + sc[1], ts2 = sc[2] + sc[3];
    float mean = ts / C;
    float var = ts2 / C - mean * mean;
    float rstd = rsqrtf(var + 1e-5f);
#pragma unroll
    for (int i = 0; i < 3; i++) {
        int c = tid + i * 128;
        float v = (x[i] - mean) * rstd * w[c] + b[c];
        if (act) v = gelu_exact(v);
        out[base + c] = v;
    }
}

// ---------- GEMM: C[M,N] = act(A[M,K] @ W[N,K]^T + bias) (+res) ----------
// A f32 or bf16 (a_bf16 flag), W f32. M%64==0, N%64==0, K%16==0.
// 256 threads, 64x64 tile, 4x4 microtile.
__global__ __launch_bounds__(256) void gemm_kernel(const void* __restrict__ Ap, int a_bf16,
                                                   const float* __restrict__ W,
                                                   const float* __restrict__ bias,
                                                   const float* __restrict__ res,
                                                   float* __restrict__ outf,
                                                   ushort_t* __restrict__ outb,
                                                   int M, int N, int K, int act) {
    __shared__ float As[16][64];
    __shared__ float Ws[16][64];
    int tid = threadIdx.x;
    int m0 = blockIdx.y * 64, n0 = blockIdx.x * 64;
    int lr = tid >> 2;          // 0..63
    int lk = (tid & 3) * 4;     // 0,4,8,12
    int tm = tid >> 4, tn = tid & 15;
    float acc[4][4] = {};
    const float* Af = (const float*)Ap;
    const ushort_t* Ab = (const ushort_t*)Ap;
    for (int k0 = 0; k0 < K; k0 += 16) {
        float a0, a1, a2, a3;
        if (a_bf16) {
            ushort4 av = *(const ushort4*)(Ab + (size_t)(m0 + lr) * K + k0 + lk);
            a0 = b2f(av.x); a1 = b2f(av.y); a2 = b2f(av.z); a3 = b2f(av.w);
        } else {
            float4 av = *(const float4*)(Af + (size_t)(m0 + lr) * K + k0 + lk);
            a0 = av.x; a1 = av.y; a2 = av.z; a3 = av.w;
        }
        float4 wv = *(const float4*)(W + (size_t)(n0 + lr) * K + k0 + lk);
        __syncthreads();
        As[lk + 0][lr] = a0; As[lk + 1][lr] = a1; As[lk + 2][lr] = a2; As[lk + 3][lr] = a3;
        Ws[lk + 0][lr] = wv.x; Ws[lk + 1][lr] = wv.y; Ws[lk + 2][lr] = wv.z; Ws[lk + 3][lr] = wv.w;
        __syncthreads();
#pragma unroll
        for (int k = 0; k < 16; k++) {
            float4 a = *(const float4*)&As[k][tm * 4];
            float4 b = *(const float4*)&Ws[k][tn * 4];
            acc[0][0] += a.x * b.x; acc[0][1] += a.x * b.y; acc[0][2] += a.x * b.z; acc[0][3] += a.x * b.w;
            acc[1][0] += a.y * b.x; acc[1][1] += a.y * b.y; acc[1][2] += a.y * b.z; acc[1][3] += a.y * b.w;
            acc[2][0] += a.z * b.x; acc[2][1] += a.z * b.y; acc[2][2] += a.z * b.z; acc[2][3] += a.z * b.w;
            acc[3][0] += a.w * b.x; acc[3][1] += a.w * b.y; acc[3][2] += a.w * b.z; acc[3][3] += a.w * b.w;
        }
    }
    float bv[4];
#pragma unroll
    for (int j = 0; j < 4; j++) bv[j] = bias ? bias[n0 + tn * 4 + j] : 0.f;
#pragma unroll
    for (int i = 0; i < 4; i++) {
        int m = m0 + tm * 4 + i;
#pragma unroll
        for (int j = 0; j < 4; j++) {
            int n = n0 + tn * 4 + j;
            float v = acc[i][j] + bv[j];
            if (act == 1) v = gelu_exact(v);
            size_t idx = (size_t)m * N + n;
            if (res) v += res[idx];
            if (outf) outf[idx] = v;
            if (outb) outb[idx] = f2b(v);
        }
    }
}

// ---------- stride-2 2x2x2 conv (branch 1). 384 threads/block, block=(b,n1out) ----------
__global__ __launch_bounds__(384) void sr1_kernel(const float* __restrict__ xa,
                                                  const float* __restrict__ w,
                                                  const float* __restrict__ bias,
                                                  float* __restrict__ y1) {
    __shared__ float patch[8 * 384];
    int bx = blockIdx.x;
    int b = bx >> 9, n1 = bx & 511;
    int ho = n1 >> 6, wo = (n1 >> 3) & 7, dz = n1 & 7;
    int tid = threadIdx.x;
#pragma unroll
    for (int k = 0; k < 8; k++) {
        int hh = 2 * ho + ((k >> 2) & 1), ww = 2 * wo + ((k >> 1) & 1), dd = 2 * dz + (k & 1);
        int n = (hh << 8) + (ww << 4) + dd;
        patch[k * 384 + tid] = xa[((size_t)b * 4096 + n) * 384 + tid];
    }
    __syncthreads();
    int co = tid;
    float acc = bias[co];
    const float* wr = w + (size_t)co * 3072;
    for (int ci = 0; ci < 384; ci++) {
        float4 w0 = *(const float4*)(wr + ci * 8);
        float4 w1 = *(const float4*)(wr + ci * 8 + 4);
        acc += patch[0 * 384 + ci] * w0.x + patch[1 * 384 + ci] * w0.y
             + patch[2 * 384 + ci] * w0.z + patch[3 * 384 + ci] * w0.w
             + patch[4 * 384 + ci] * w1.x + patch[5 * 384 + ci] * w1.y
             + patch[6 * 384 + ci] * w1.z + patch[7 * 384 + ci] * w1.w;
    }
    y1[((size_t)b * 512 + n1) * 384 + co] = acc;
}

// ---------- depthwise 3x3x3 SAME residual conv on V: vout = v + (conv(v)+bias) ----------
// vin points at v channels (row stride 384 bf16), vout row stride 192 bf16.
__global__ void dwconv_kernel(const ushort_t* __restrict__ vin,
                              const float* __restrict__ wt,
                              const float* __restrict__ bias,
                              ushort_t* __restrict__ vout,
                              int Hs, int Wsz, int Ds, int S, int total) {
    int gid = blockIdx.x * 256 + threadIdx.x;
    if (gid >= total) return;
    int c2 = gid % 192;
    int r = gid / 192;
    int n = r % S;
    int b = r / S;
    int dz = n % Ds, wy = (n / Ds) % Wsz, hx = n / (Wsz * Ds);
    float center = b2f(vin[(size_t)(b * S + n) * 384 + c2]);
    float acc = bias[c2];
    for (int kh = -1; kh <= 1; kh++) {
        int h2 = hx + kh; if (h2 < 0 || h2 >= Hs) continue;
        for (int kw = -1; kw <= 1; kw++) {
            int w2 = wy + kw; if (w2 < 0 || w2 >= Wsz) continue;
            for (int kd = -1; kd <= 1; kd++) {
                int d2 = dz + kd; if (d2 < 0 || d2 >= Ds) continue;
                int nn = (h2 * Wsz + w2) * Ds + d2;
                acc += b2f(vin[(size_t)(b * S + nn) * 384 + c2]) *
                       wt[c2 * 27 + (kh + 1) * 9 + (kw + 1) * 3 + (kd + 1)];
            }
        }
    }
    vout[(size_t)(b * S + n) * 192 + c2] = f2b(center + acc);
}

// ---------- attention: one block per (b, head_local, q-row); scores in LDS ----------
// q f32 [B][N][384]; K bf16 [B][NK][384] (head offset hl*48); V bf16 [B][NK][192].
__global__ __launch_bounds__(256) void attn_kernel(const float* __restrict__ q,
                                                   const ushort_t* __restrict__ kbuf,
                                                   const ushort_t* __restrict__ vbuf,
                                                   float* __restrict__ obuf,
                                                   int NK, int head_base, int out_base) {
    extern __shared__ float smem[];
    const int N = 4096;
    float* sc = smem;            // NK scores
    float* qs = smem + NK;       // 48
    float* wr = qs + 48;         // 200 scratch (4 reduce slots / 4x48 partials)
    int tid = threadIdx.x;
    int qrow = blockIdx.x, hl = blockIdx.y, b = blockIdx.z;
    const float scale = 0.14433756729740643f;  // 48^-0.5
    int qoff = (head_base + hl) * 48;
    if (tid < 48) qs[tid] = q[((size_t)b * N + qrow) * 384 + qoff + tid];
    __syncthreads();

    const ushort_t* kb = kbuf + (size_t)b * NK * 384 + hl * 48;
    float lmax = -1e30f;
    for (int key = tid; key < NK; key += 256) {
        const ushort_t* kr = kb + (size_t)key * 384;
        float s = 0.f;
#pragma unroll
        for (int v = 0; v < 6; v++) {
            uint4 pk = *(const uint4*)(kr + v * 8);
            s += qs[v * 8 + 0] * blo(pk.x) + qs[v * 8 + 1] * bhi(pk.x)
               + qs[v * 8 + 2] * blo(pk.y) + qs[v * 8 + 3] * bhi(pk.y)
               + qs[v * 8 + 4] * blo(pk.z) + qs[v * 8 + 5] * bhi(pk.z)
               + qs[v * 8 + 6] * blo(pk.w) + qs[v * 8 + 7] * bhi(pk.w);
        }
        s *= scale;
        sc[key] = s;
        lmax = fmaxf(lmax, s);
    }
    // block max
    int lane = tid & 63, wid = tid >> 6;
    float v = lmax;
    for (int off = 32; off; off >>= 1) v = fmaxf(v, __shfl_down(v, off));
    if (lane == 0) wr[wid] = v;
    __syncthreads();
    float rmax = fmaxf(fmaxf(wr[0], wr[1]), fmaxf(wr[2], wr[3]));
    __syncthreads();
    // exp + sum
    float lsum = 0.f;
    for (int key = tid; key < NK; key += 256) {
        float p = __expf(sc[key] - rmax);
        sc[key] = p;
        lsum += p;
    }
    v = lsum;
    for (int off = 32; off; off >>= 1) v += __shfl_down(v, off);
    if (lane == 0) wr[wid] = v;
    __syncthreads();
    float rsum = wr[0] + wr[1] + wr[2] + wr[3];
    __syncthreads();
    // PV
    float acc[48];
#pragma unroll
    for (int d = 0; d < 48; d++) acc[d] = 0.f;
    const ushort_t* vb = vbuf + (size_t)b * NK * 192 + hl * 48;
    for (int key = tid; key < NK; key += 256) {
        float p = sc[key];
        const ushort_t* vrow = vb + (size_t)key * 192;
#pragma unroll
        for (int vv = 0; vv < 6; vv++) {
            uint4 pv = *(const uint4*)(vrow + vv * 8);
            acc[vv * 8 + 0] += p * blo(pv.x); acc[vv * 8 + 1] += p * bhi(pv.x);
            acc[vv * 8 + 2] += p * blo(pv.y); acc[vv * 8 + 3] += p * bhi(pv.y);
            acc[vv * 8 + 4] += p * blo(pv.z); acc[vv * 8 + 5] += p * bhi(pv.z);
            acc[vv * 8 + 6] += p * blo(pv.w); acc[vv * 8 + 7] += p * bhi(pv.w);
        }
    }
#pragma unroll
    for (int d = 0; d < 48; d++) {
        float t = acc[d];
        for (int off = 32; off; off >>= 1) t += __shfl_down(t, off);
        acc[d] = t;
    }
    if (lane == 0) {
#pragma unroll
        for (int d = 0; d < 48; d++) wr[wid * 48 + d] = acc[d];
    }
    __syncthreads();
    if (tid < 48) {
        float o = (wr[tid] + wr[48 + tid] + wr[96 + tid] + wr[144 + tid]) / rsum;
        obuf[((size_t)b * N + qrow) * 384 + out_base + hl * 48 + tid] = o;
    }
}

// ---------- host ----------
extern "C" void kernel_launch(void* const* d_in, const int* in_sizes, int n_in,
                              void* d_out, int out_size, void* d_ws, size_t ws_size,
                              hipStream_t stream) {
    const int B = 2, N = 4096, C = 384, N1 = 512, HID = 1536;
    const float* x      = (const float*)d_in[0];
    const float* ln1_w  = (const float*)d_in[1];
    const float* ln1_b  = (const float*)d_in[2];
    const float* q_w    = (const float*)d_in[3];
    const float* sr1_w  = (const float*)d_in[4];
    const float* sr1_b  = (const float*)d_in[5];
    const float* n1_w   = (const float*)d_in[6];
    const float* n1_b   = (const float*)d_in[7];
    const float* sr2_w  = (const float*)d_in[8];
    const float* sr2_b  = (const float*)d_in[9];
    const float* n2_w   = (const float*)d_in[10];
    const float* n2_b   = (const float*)d_in[11];
    const float* kv1_w  = (const float*)d_in[12];
    const float* kv2_w  = (const float*)d_in[13];
    const float* lc1_w  = (const float*)d_in[14];
    const float* lc1_b  = (const float*)d_in[15];
    const float* lc2_w  = (const float*)d_in[16];
    const float* lc2_b  = (const float*)d_in[17];
    const float* proj_w = (const float*)d_in[18];
    const float* proj_b = (const float*)d_in[19];
    const float* ln2_w  = (const float*)d_in[20];
    const float* ln2_b  = (const float*)d_in[21];
    const float* fc1_w  = (const float*)d_in[22];
    const float* fc1_b  = (const float*)d_in[23];
    const float* fc2_w  = (const float*)d_in[24];
    const float* fc2_b  = (const float*)d_in[25];
    float* out = (float*)d_out;   // reference output dtype is float32

    char* ws = (char*)d_ws;
    // arena (bytes), total ~72 MB.
    float*    xa    = (float*)(ws);                         // [B,N,C] f32; reused as O
    float*    qb    = (float*)(ws + 12582912);              // [B,N,C] f32; reused as XRES
    float*    x2b   = (float*)(ws + 25165824);              // [B,N,C] f32 (y2->x2); reused as XM
    ushort_t* kv2   = (ushort_t*)(ws + 37748736);           // [B,N,C] bf16
    float*    x1b   = (float*)(ws + 44040192);              // [B,N1,C] f32 (y1->x1)
    ushort_t* kv1   = (ushort_t*)(ws + 45613056);           // [B,N1,C] bf16
    ushort_t* vmod2 = (ushort_t*)(ws + 46399488);           // [B,N,192] bf16
    ushort_t* vmod1 = (ushort_t*)(ws + 49545216);           // [B,N1,192] bf16
    ushort_t* hid   = (ushort_t*)(ws + 49938432);           // [B,N,1536] bf16
    float*    Obuf  = xa;
    float*    xres  = qb;
    float*    xm    = x2b;

    // 1. xa = LN(x)
    ln_kernel<<<B * N, 128, 0, stream>>>(x, ln1_w, ln1_b, xa, 0);
    // 2. q = xa @ q_w^T
    gemm_kernel<<<dim3(C / 64, B * N / 64), 256, 0, stream>>>(xa, 0, q_w, nullptr, nullptr,
                                                              qb, nullptr, B * N, C, C, 0);
    // 3. y2 = xa @ sr2_w^T + b
    gemm_kernel<<<dim3(C / 64, B * N / 64), 256, 0, stream>>>(xa, 0, sr2_w, sr2_b, nullptr,
                                                              x2b, nullptr, B * N, C, C, 0);
    // 4. x2 = gelu(LN(y2)) in place
    ln_kernel<<<B * N, 128, 0, stream>>>(x2b, n2_w, n2_b, x2b, 1);
    // 5. y1 = conv2x2x2s2(xa)
    sr1_kernel<<<B * N1, 384, 0, stream>>>(xa, sr1_w, sr1_b, x1b);
    // 6. x1 = gelu(LN(y1)) in place
    ln_kernel<<<B * N1, 128, 0, stream>>>(x1b, n1_w, n1_b, x1b, 1);
    // 7. kv2 = x2 @ kv2_w^T  (bf16 out)
    gemm_kernel<<<dim3(C / 64, B * N / 64), 256, 0, stream>>>(x2b, 0, kv2_w, nullptr, nullptr,
                                                              nullptr, kv2, B * N, C, C, 0);
    // 8. kv1 = x1 @ kv1_w^T  (bf16 out)
    gemm_kernel<<<dim3(C / 64, B * N1 / 64), 256, 0, stream>>>(x1b, 0, kv1_w, nullptr, nullptr,
                                                               nullptr, kv1, B * N1, C, C, 0);
    // 9/10. vmod = v + dwconv3(v)
    {
        int total2 = B * N * 192;
        dwconv_kernel<<<(total2 + 255) / 256, 256, 0, stream>>>(kv2 + 192, lc2_w, lc2_b, vmod2,
                                                                16, 16, 16, N, total2);
        int total1 = B * N1 * 192;
        dwconv_kernel<<<(total1 + 255) / 256, 256, 0, stream>>>(kv1 + 192, lc1_w, lc1_b, vmod1,
                                                                8, 8, 8, N1, total1);
    }
    // 11. attention branch1 (NK=512, heads 0-3 -> out ch 0-191)
    attn_kernel<<<dim3(N, 4, B), 256, (512 + 48 + 200) * 4, stream>>>(qb, kv1, vmod1, Obuf,
                                                                      512, 0, 0);
    // 12. attention branch2 (NK=4096, heads 4-7 -> out ch 192-383)
    attn_kernel<<<dim3(N, 4, B), 256, (4096 + 48 + 200) * 4, stream>>>(qb, kv2, vmod2, Obuf,
                                                                       4096, 4, 192);
    // 13. xres = x + O @ proj_w^T + proj_b
    gemm_kernel<<<dim3(C / 64, B * N / 64), 256, 0, stream>>>(Obuf, 0, proj_w, proj_b, x,
                                                              xres, nullptr, B * N, C, C, 0);
    // 14. xm = LN(xres)
    ln_kernel<<<B * N, 128, 0, stream>>>(xres, ln2_w, ln2_b, xm, 0);
    // 15. hid = gelu(xm @ fc1^T + b)  (bf16 out)
    gemm_kernel<<<dim3(HID / 64, B * N / 64), 256, 0, stream>>>(xm, 0, fc1_w, fc1_b, nullptr,
                                                                nullptr, hid, B * N, HID, C, 1);
    // 16. out = xres + hid @ fc2^T + b   (f32 out -> d_out)
    gemm_kernel<<<dim3(C / 64, B * N / 64), 256, 0, stream>>>(hid, 1, fc2_w, fc2_b, xres,
                                                              out, nullptr, B * N, C, HID, 0);
}

// Round 5
// 1543.541 us; speedup vs baseline: 2.9040x; 2.9040x over previous
//
#include <hip/hip_runtime.h>

typedef unsigned short ushort_t;
typedef unsigned int uint_t;
typedef __bf16 bf16_t;
typedef __bf16 bf16x8 __attribute__((ext_vector_type(8)));
typedef float f32x4 __attribute__((ext_vector_type(4)));

// ---------- helpers ----------
__device__ __forceinline__ float b2f(ushort_t u) {
    union { uint_t i; float f; } v; v.i = ((uint_t)u) << 16; return v.f;
}
__device__ __forceinline__ ushort_t f2b(float f) {
    union { float f; uint_t i; } v; v.f = f;
    uint_t r = v.i + 0x7fffu + ((v.i >> 16) & 1u);
    return (ushort_t)(r >> 16);
}
__device__ __forceinline__ float gelu_exact(float x) {
    return 0.5f * x * (1.0f + erff(x * 0.70710678118654752f));
}

// ---------- LayerNorm (+ optional GELU); C = 384, 128 threads, 1 block/row ----------
__global__ __launch_bounds__(128) void ln_kernel(const float* __restrict__ in,
                                                 const float* __restrict__ w,
                                                 const float* __restrict__ b,
                                                 float* __restrict__ out, int act) {
    const int C = 384;
    int row = blockIdx.x, tid = threadIdx.x;
    size_t base = (size_t)row * C;
    float x[3], s = 0.f, s2 = 0.f;
#pragma unroll
    for (int i = 0; i < 3; i++) {
        int c = tid + i * 128;
        float v = in[base + c];
        x[i] = v; s += v; s2 += v * v;
    }
    for (int off = 32; off; off >>= 1) { s += __shfl_down(s, off); s2 += __shfl_down(s2, off); }
    __shared__ float sc[4];
    int lane = tid & 63, wid = tid >> 6;
    if (lane == 0) { sc[wid] = s; sc[wid + 2] = s2; }
    __syncthreads();
    float ts = sc[0] + sc[1], ts2 = sc[2] + sc[3];
    float mean = ts / C;
    float var = ts2 / C - mean * mean;
    float rstd = rsqrtf(var + 1e-5f);
#pragma unroll
    for (int i = 0; i < 3; i++) {
        int c = tid + i * 128;
        float v = (x[i] - mean) * rstd * w[c] + b[c];
        if (act) v = gelu_exact(v);
        out[base + c] = v;
    }
}

// ---------- GEMM: C[M,N] = act(A[M,K] @ W[N,K]^T + bias) (+res) ----------
__global__ __launch_bounds__(256) void gemm_kernel(const void* __restrict__ Ap, int a_bf16,
                                                   const float* __restrict__ W,
                                                   const float* __restrict__ bias,
                                                   const float* __restrict__ res,
                                                   float* __restrict__ outf,
                                                   ushort_t* __restrict__ outb,
                                                   int M, int N, int K, int act) {
    __shared__ float As[16][64];
    __shared__ float Ws[16][64];
    int tid = threadIdx.x;
    int m0 = blockIdx.y * 64, n0 = blockIdx.x * 64;
    int lr = tid >> 2;          // 0..63
    int lk = (tid & 3) * 4;     // 0,4,8,12
    int tm = tid >> 4, tn = tid & 15;
    float acc[4][4] = {};
    const float* Af = (const float*)Ap;
    const ushort_t* Ab = (const ushort_t*)Ap;
    for (int k0 = 0; k0 < K; k0 += 16) {
        float a0, a1, a2, a3;
        if (a_bf16) {
            ushort4 av = *(const ushort4*)(Ab + (size_t)(m0 + lr) * K + k0 + lk);
            a0 = b2f(av.x); a1 = b2f(av.y); a2 = b2f(av.z); a3 = b2f(av.w);
        } else {
            float4 av = *(const float4*)(Af + (size_t)(m0 + lr) * K + k0 + lk);
            a0 = av.x; a1 = av.y; a2 = av.z; a3 = av.w;
        }
        float4 wv = *(const float4*)(W + (size_t)(n0 + lr) * K + k0 + lk);
        __syncthreads();
        As[lk + 0][lr] = a0; As[lk + 1][lr] = a1; As[lk + 2][lr] = a2; As[lk + 3][lr] = a3;
        Ws[lk + 0][lr] = wv.x; Ws[lk + 1][lr] = wv.y; Ws[lk + 2][lr] = wv.z; Ws[lk + 3][lr] = wv.w;
        __syncthreads();
#pragma unroll
        for (int k = 0; k < 16; k++) {
            float4 a = *(const float4*)&As[k][tm * 4];
            float4 b = *(const float4*)&Ws[k][tn * 4];
            acc[0][0] += a.x * b.x; acc[0][1] += a.x * b.y; acc[0][2] += a.x * b.z; acc[0][3] += a.x * b.w;
            acc[1][0] += a.y * b.x; acc[1][1] += a.y * b.y; acc[1][2] += a.y * b.z; acc[1][3] += a.y * b.w;
            acc[2][0] += a.z * b.x; acc[2][1] += a.z * b.y; acc[2][2] += a.z * b.z; acc[2][3] += a.z * b.w;
            acc[3][0] += a.w * b.x; acc[3][1] += a.w * b.y; acc[3][2] += a.w * b.z; acc[3][3] += a.w * b.w;
        }
    }
    float bv[4];
#pragma unroll
    for (int j = 0; j < 4; j++) bv[j] = bias ? bias[n0 + tn * 4 + j] : 0.f;
#pragma unroll
    for (int i = 0; i < 4; i++) {
        int m = m0 + tm * 4 + i;
#pragma unroll
        for (int j = 0; j < 4; j++) {
            int n = n0 + tn * 4 + j;
            float v = acc[i][j] + bv[j];
            if (act == 1) v = gelu_exact(v);
            size_t idx = (size_t)m * N + n;
            if (res) v += res[idx];
            if (outf) outf[idx] = v;
            if (outb) outb[idx] = f2b(v);
        }
    }
}

// ---------- stride-2 2x2x2 conv (branch 1). 384 threads/block ----------
__global__ __launch_bounds__(384) void sr1_kernel(const float* __restrict__ xa,
                                                  const float* __restrict__ w,
                                                  const float* __restrict__ bias,
                                                  float* __restrict__ y1) {
    __shared__ float patch[8 * 384];
    int bx = blockIdx.x;
    int b = bx >> 9, n1 = bx & 511;
    int ho = n1 >> 6, wo = (n1 >> 3) & 7, dz = n1 & 7;
    int tid = threadIdx.x;
#pragma unroll
    for (int k = 0; k < 8; k++) {
        int hh = 2 * ho + ((k >> 2) & 1), ww = 2 * wo + ((k >> 1) & 1), dd = 2 * dz + (k & 1);
        int n = (hh << 8) + (ww << 4) + dd;
        patch[k * 384 + tid] = xa[((size_t)b * 4096 + n) * 384 + tid];
    }
    __syncthreads();
    int co = tid;
    float acc = bias[co];
    const float* wr = w + (size_t)co * 3072;
    for (int ci = 0; ci < 384; ci++) {
        float4 w0 = *(const float4*)(wr + ci * 8);
        float4 w1 = *(const float4*)(wr + ci * 8 + 4);
        acc += patch[0 * 384 + ci] * w0.x + patch[1 * 384 + ci] * w0.y
             + patch[2 * 384 + ci] * w0.z + patch[3 * 384 + ci] * w0.w
             + patch[4 * 384 + ci] * w1.x + patch[5 * 384 + ci] * w1.y
             + patch[6 * 384 + ci] * w1.z + patch[7 * 384 + ci] * w1.w;
    }
    y1[((size_t)b * 512 + n1) * 384 + co] = acc;
}

// ---------- depthwise 3x3x3 SAME residual conv on V ----------
__global__ void dwconv_kernel(const ushort_t* __restrict__ vin,
                              const float* __restrict__ wt,
                              const float* __restrict__ bias,
                              ushort_t* __restrict__ vout,
                              int Hs, int Wsz, int Ds, int S, int total) {
    int gid = blockIdx.x * 256 + threadIdx.x;
    if (gid >= total) return;
    int c2 = gid % 192;
    int r = gid / 192;
    int n = r % S;
    int b = r / S;
    int dz = n % Ds, wy = (n / Ds) % Wsz, hx = n / (Wsz * Ds);
    float center = b2f(vin[(size_t)(b * S + n) * 384 + c2]);
    float acc = bias[c2];
    for (int kh = -1; kh <= 1; kh++) {
        int h2 = hx + kh; if (h2 < 0 || h2 >= Hs) continue;
        for (int kw = -1; kw <= 1; kw++) {
            int w2 = wy + kw; if (w2 < 0 || w2 >= Wsz) continue;
            for (int kd = -1; kd <= 1; kd++) {
                int d2 = dz + kd; if (d2 < 0 || d2 >= Ds) continue;
                int nn = (h2 * Wsz + w2) * Ds + d2;
                acc += b2f(vin[(size_t)(b * S + nn) * 384 + c2]) *
                       wt[c2 * 27 + (kh + 1) * 9 + (kw + 1) * 3 + (kd + 1)];
            }
        }
    }
    vout[(size_t)(b * S + n) * 192 + c2] = f2b(center + acc);
}

// ---------- MFMA flash attention ----------
// 64 q-rows per block, 4 waves, KBLK=64, hd=48 padded to 64.
// q bf16 [B,N,384] (ch (head_base+hl)*48); K bf16 [B,NK,384] (ch hl*48);
// V bf16 [B,NK,192] (ch hl*48); O f32 [B,N,384] (ch out_base+hl*48).
__global__ __launch_bounds__(256) void attn_mfma_kernel(
    const ushort_t* __restrict__ qbuf,
    const ushort_t* __restrict__ kvbuf,
    const ushort_t* __restrict__ vbuf,
    float* __restrict__ obuf,
    int NK, int head_base, int out_base)
{
    __shared__ bf16_t Q_lds[64][72];   // 144B row stride = 16B-aligned, 2-way bank alias (free)
    __shared__ bf16_t K_lds[64][72];
    __shared__ bf16_t VT_lds[48][72];  // V transposed: VT[d][j]
    __shared__ bf16_t P_lds[64][72];

    const int N = 4096;
    int tid = threadIdx.x;
    int q0 = blockIdx.x * 64, hl = blockIdx.y, b = blockIdx.z;
    int wave = tid >> 6, lane = tid & 63, g = lane >> 4, c = lane & 15;
    const float scale = 0.14433756729740643f;  // 48^-0.5

    // ---- stage Q tile (once): 64 rows x 48 bf16 = 64 x 24 dwords ----
    {
        const ushort_t* qsrc = qbuf + ((size_t)b * N + q0) * 384 + (head_base + hl) * 48;
        for (int u = tid; u < 1536; u += 256) {
            int r = u / 24, cp = u % 24;
            *(uint_t*)&Q_lds[r][cp * 2] = *(const uint_t*)(qsrc + (size_t)r * 384 + cp * 2);
        }
        for (int u = tid; u < 512; u += 256) {
            int r = u / 8, cp = u % 8;
            *(uint_t*)&Q_lds[r][48 + cp * 2] = 0;
        }
    }

    f32x4 of[3];
#pragma unroll
    for (int dt = 0; dt < 3; dt++) of[dt] = f32x4{0.f, 0.f, 0.f, 0.f};
    float m_run[4] = {-1e30f, -1e30f, -1e30f, -1e30f};
    float l_run[4] = {0.f, 0.f, 0.f, 0.f};

    const ushort_t* ksrc0 = kvbuf + (size_t)b * NK * 384 + hl * 48;
    const ushort_t* vsrc0 = vbuf + (size_t)b * NK * 192 + hl * 48;
    int nkt = NK >> 6;

    for (int kt = 0; kt < nkt; kt++) {
        __syncthreads();   // prev PV done (and Q staged on first iter)
        // ---- stage K tile [64][48] (24 dwords/row) + zero-pad cols 48..63 ----
        const ushort_t* ksrc = ksrc0 + (size_t)kt * 64 * 384;
        for (int u = tid; u < 1536; u += 256) {
            int r = u / 24, cp = u % 24;
            *(uint_t*)&K_lds[r][cp * 2] = *(const uint_t*)(ksrc + (size_t)r * 384 + cp * 2);
        }
        for (int u = tid; u < 512; u += 256) {
            int r = u / 8, cp = u % 8;
            *(uint_t*)&K_lds[r][48 + cp * 2] = 0;
        }
        // ---- stage V tile transposed: VT[d][j] = V[j][d], 64 j x 24 dwords ----
        const ushort_t* vsrc = vsrc0 + (size_t)kt * 64 * 192;
        for (int u = tid; u < 1536; u += 256) {
            int j = u / 24, dp = u % 24;
            uint_t val = *(const uint_t*)(vsrc + (size_t)j * 192 + dp * 2);
            *(ushort_t*)&VT_lds[dp * 2 + 0][j] = (ushort_t)(val & 0xffffu);
            *(ushort_t*)&VT_lds[dp * 2 + 1][j] = (ushort_t)(val >> 16);
        }
        __syncthreads();

        // ---- S = Q K^T (wave computes rows 16w..16w+15 x cols 0..63) ----
        f32x4 sf[4];
#pragma unroll
        for (int t = 0; t < 4; t++) sf[t] = f32x4{0.f, 0.f, 0.f, 0.f};
        bf16x8 aq0 = *(bf16x8*)&Q_lds[16 * wave + c][g * 8];
        bf16x8 aq1 = *(bf16x8*)&Q_lds[16 * wave + c][32 + g * 8];
#pragma unroll
        for (int t = 0; t < 4; t++) {
            bf16x8 bk0 = *(bf16x8*)&K_lds[16 * t + c][g * 8];
            bf16x8 bk1 = *(bf16x8*)&K_lds[16 * t + c][32 + g * 8];
            sf[t] = __builtin_amdgcn_mfma_f32_16x16x32_bf16(aq0, bk0, sf[t], 0, 0, 0);
            sf[t] = __builtin_amdgcn_mfma_f32_16x16x32_bf16(aq1, bk1, sf[t], 0, 0, 0);
        }

        // ---- online softmax (row = 16w + 4g + i) ----
        float mx[4];
#pragma unroll
        for (int i = 0; i < 4; i++)
            mx[i] = fmaxf(fmaxf(sf[0][i], sf[1][i]), fmaxf(sf[2][i], sf[3][i])) * scale;
#pragma unroll
        for (int m = 1; m < 16; m <<= 1) {
#pragma unroll
            for (int i = 0; i < 4; i++) mx[i] = fmaxf(mx[i], __shfl_xor(mx[i], m));
        }
        float fct[4];
#pragma unroll
        for (int i = 0; i < 4; i++) {
            float mn = fmaxf(m_run[i], mx[i]);
            fct[i] = __expf(m_run[i] - mn);
            m_run[i] = mn;
        }
        float rs[4] = {0.f, 0.f, 0.f, 0.f};
#pragma unroll
        for (int t = 0; t < 4; t++) {
#pragma unroll
            for (int i = 0; i < 4; i++) {
                float p = __expf(sf[t][i] * scale - m_run[i]);
                rs[i] += p;
                P_lds[16 * wave + 4 * g + i][16 * t + c] = (bf16_t)p;
            }
        }
#pragma unroll
        for (int m = 1; m < 16; m <<= 1) {
#pragma unroll
            for (int i = 0; i < 4; i++) rs[i] += __shfl_xor(rs[i], m);
        }
#pragma unroll
        for (int i = 0; i < 4; i++) l_run[i] = l_run[i] * fct[i] + rs[i];
#pragma unroll
        for (int dt = 0; dt < 3; dt++) {
#pragma unroll
            for (int i = 0; i < 4; i++) of[dt][i] *= fct[i];
        }
        __syncthreads();   // P writes visible (wave-local reads, kept for safety)

        // ---- O += P V ----
        bf16x8 pa0 = *(bf16x8*)&P_lds[16 * wave + c][g * 8];
        bf16x8 pa1 = *(bf16x8*)&P_lds[16 * wave + c][32 + g * 8];
#pragma unroll
        for (int dt = 0; dt < 3; dt++) {
            bf16x8 v0 = *(bf16x8*)&VT_lds[dt * 16 + c][g * 8];
            bf16x8 v1 = *(bf16x8*)&VT_lds[dt * 16 + c][32 + g * 8];
            of[dt] = __builtin_amdgcn_mfma_f32_16x16x32_bf16(pa0, v0, of[dt], 0, 0, 0);
            of[dt] = __builtin_amdgcn_mfma_f32_16x16x32_bf16(pa1, v1, of[dt], 0, 0, 0);
        }
    }

    // ---- epilogue ----
#pragma unroll
    for (int dt = 0; dt < 3; dt++) {
#pragma unroll
        for (int i = 0; i < 4; i++) {
            int row = q0 + 16 * wave + 4 * g + i;
            int col = out_base + hl * 48 + dt * 16 + c;
            obuf[((size_t)b * N + row) * 384 + col] = of[dt][i] / l_run[i];
        }
    }
}

// ---------- host ----------
extern "C" void kernel_launch(void* const* d_in, const int* in_sizes, int n_in,
                              void* d_out, int out_size, void* d_ws, size_t ws_size,
                              hipStream_t stream) {
    const int B = 2, N = 4096, C = 384, N1 = 512, HID = 1536;
    const float* x      = (const float*)d_in[0];
    const float* ln1_w  = (const float*)d_in[1];
    const float* ln1_b  = (const float*)d_in[2];
    const float* q_w    = (const float*)d_in[3];
    const float* sr1_w  = (const float*)d_in[4];
    const float* sr1_b  = (const float*)d_in[5];
    const float* n1_w   = (const float*)d_in[6];
    const float* n1_b   = (const float*)d_in[7];
    const float* sr2_w  = (const float*)d_in[8];
    const float* sr2_b  = (const float*)d_in[9];
    const float* n2_w   = (const float*)d_in[10];
    const float* n2_b   = (const float*)d_in[11];
    const float* kv1_w  = (const float*)d_in[12];
    const float* kv2_w  = (const float*)d_in[13];
    const float* lc1_w  = (const float*)d_in[14];
    const float* lc1_b  = (const float*)d_in[15];
    const float* lc2_w  = (const float*)d_in[16];
    const float* lc2_b  = (const float*)d_in[17];
    const float* proj_w = (const float*)d_in[18];
    const float* proj_b = (const float*)d_in[19];
    const float* ln2_w  = (const float*)d_in[20];
    const float* ln2_b  = (const float*)d_in[21];
    const float* fc1_w  = (const float*)d_in[22];
    const float* fc1_b  = (const float*)d_in[23];
    const float* fc2_w  = (const float*)d_in[24];
    const float* fc2_b  = (const float*)d_in[25];
    float* out = (float*)d_out;

    char* ws = (char*)d_ws;
    // arena (bytes), total ~68.8 MB
    float*    xa    = (float*)(ws);                     // [B,N,C] f32; -> Obuf -> xm
    float*    x2b   = (float*)(ws + 12582912);          // [B,N,C] f32; -> xres
    ushort_t* qbB   = (ushort_t*)(ws + 25165824);       // [B,N,C] bf16
    ushort_t* kv2   = (ushort_t*)(ws + 31457280);       // [B,N,C] bf16
    ushort_t* vmod2 = (ushort_t*)(ws + 37748736);       // [B,N,192] bf16
    float*    x1b   = (float*)(ws + 40894464);          // [B,N1,C] f32
    ushort_t* kv1   = (ushort_t*)(ws + 42467328);       // [B,N1,C] bf16
    ushort_t* vmod1 = (ushort_t*)(ws + 43253760);       // [B,N1,192] bf16
    ushort_t* hid   = (ushort_t*)(ws + 43646976);       // [B,N,1536] bf16
    float*    Obuf  = xa;
    float*    xres  = x2b;
    float*    xm    = xa;

    // 1. xa = LN(x)
    ln_kernel<<<B * N, 128, 0, stream>>>(x, ln1_w, ln1_b, xa, 0);
    // 2. q = xa @ q_w^T (bf16 out)
    gemm_kernel<<<dim3(C / 64, B * N / 64), 256, 0, stream>>>(xa, 0, q_w, nullptr, nullptr,
                                                              nullptr, qbB, B * N, C, C, 0);
    // 3. y2 = xa @ sr2_w^T + b
    gemm_kernel<<<dim3(C / 64, B * N / 64), 256, 0, stream>>>(xa, 0, sr2_w, sr2_b, nullptr,
                                                              x2b, nullptr, B * N, C, C, 0);
    // 4. x2 = gelu(LN(y2)) in place
    ln_kernel<<<B * N, 128, 0, stream>>>(x2b, n2_w, n2_b, x2b, 1);
    // 5. y1 = conv2x2x2s2(xa)
    sr1_kernel<<<B * N1, 384, 0, stream>>>(xa, sr1_w, sr1_b, x1b);
    // 6. x1 = gelu(LN(y1)) in place
    ln_kernel<<<B * N1, 128, 0, stream>>>(x1b, n1_w, n1_b, x1b, 1);
    // 7. kv2 = x2 @ kv2_w^T (bf16 out)
    gemm_kernel<<<dim3(C / 64, B * N / 64), 256, 0, stream>>>(x2b, 0, kv2_w, nullptr, nullptr,
                                                              nullptr, kv2, B * N, C, C, 0);
    // 8. kv1 = x1 @ kv1_w^T (bf16 out)
    gemm_kernel<<<dim3(C / 64, B * N1 / 64), 256, 0, stream>>>(x1b, 0, kv1_w, nullptr, nullptr,
                                                               nullptr, kv1, B * N1, C, C, 0);
    // 9/10. vmod = v + dwconv3(v)
    {
        int total2 = B * N * 192;
        dwconv_kernel<<<(total2 + 255) / 256, 256, 0, stream>>>(kv2 + 192, lc2_w, lc2_b, vmod2,
                                                                16, 16, 16, N, total2);
        int total1 = B * N1 * 192;
        dwconv_kernel<<<(total1 + 255) / 256, 256, 0, stream>>>(kv1 + 192, lc1_w, lc1_b, vmod1,
                                                                8, 8, 8, N1, total1);
    }
    // 11. attention branch1 (NK=512, heads 0-3 -> out ch 0-191)
    attn_mfma_kernel<<<dim3(N / 64, 4, B), 256, 0, stream>>>(qbB, kv1, vmod1, Obuf, 512, 0, 0);
    // 12. attention branch2 (NK=4096, heads 4-7 -> out ch 192-383)
    attn_mfma_kernel<<<dim3(N / 64, 4, B), 256, 0, stream>>>(qbB, kv2, vmod2, Obuf, 4096, 4, 192);
    // 13. xres = x + O @ proj_w^T + proj_b
    gemm_kernel<<<dim3(C / 64, B * N / 64), 256, 0, stream>>>(Obuf, 0, proj_w, proj_b, x,
                                                              xres, nullptr, B * N, C, C, 0);
    // 14. xm = LN(xres)   (xm aliases xa; Obuf no longer needed)
    ln_kernel<<<B * N, 128, 0, stream>>>(xres, ln2_w, ln2_b, xm, 0);
    // 15. hid = gelu(xm @ fc1^T + b) (bf16 out)
    gemm_kernel<<<dim3(HID / 64, B * N / 64), 256, 0, stream>>>(xm, 0, fc1_w, fc1_b, nullptr,
                                                                nullptr, hid, B * N, HID, C, 1);
    // 16. out = xres + hid @ fc2^T + b (f32 out -> d_out)
    gemm_kernel<<<dim3(C / 64, B * N / 64), 256, 0, stream>>>(hid, 1, fc2_w, fc2_b, xres,
                                                              out, nullptr, B * N, C, HID, 0);
}

// Round 6
// 717.945 us; speedup vs baseline: 6.2434x; 2.1499x over previous
//
#include <hip/hip_runtime.h>

typedef unsigned short ushort_t;
typedef unsigned int uint_t;
typedef __bf16 bf16_t;
typedef __bf16 bf16x8 __attribute__((ext_vector_type(8)));
typedef float f32x4 __attribute__((ext_vector_type(4)));

// ---------- helpers ----------
__device__ __forceinline__ float b2f(ushort_t u) {
    union { uint_t i; float f; } v; v.i = ((uint_t)u) << 16; return v.f;
}
__device__ __forceinline__ ushort_t f2b(float f) {
    union { float f; uint_t i; } v; v.f = f;
    uint_t r = v.i + 0x7fffu + ((v.i >> 16) & 1u);
    return (ushort_t)(r >> 16);
}
__device__ __forceinline__ float gelu_exact(float x) {
    return 0.5f * x * (1.0f + erff(x * 0.70710678118654752f));
}

// ---------- f32 -> bf16 convert ----------
__global__ void cvt_kernel(const float* __restrict__ src, ushort_t* __restrict__ dst, int n) {
    int i = blockIdx.x * 256 + threadIdx.x;
    if (i < n) dst[i] = f2b(src[i]);
}

// ---------- sr1 weight reorder: w[co][ci][kk] -> w2[co][kk*384+ci] (bf16) ----------
__global__ void sr1w_kernel(const float* __restrict__ src, ushort_t* __restrict__ dst, int n) {
    int gid = blockIdx.x * 256 + threadIdx.x;
    if (gid >= n) return;
    int co = gid / 3072, r = gid % 3072, kk = r / 384, ci = r % 384;
    dst[gid] = f2b(src[((size_t)co * 384 + ci) * 8 + kk]);
}

// ---------- im2col for sr1: A1[b*512+n1][kk*384+ci] = xa_bf[b, n(n1,kk), ci] ----------
__global__ void im2col_kernel(const ushort_t* __restrict__ xa, ushort_t* __restrict__ A1) {
    int gid = blockIdx.x * 256 + threadIdx.x;
    if (gid >= 1024 * 3072) return;
    int m = gid / 3072, r = gid % 3072, kk = r / 384, ci = r % 384;
    int b = m >> 9, n1 = m & 511;
    int ho = n1 >> 6, wo = (n1 >> 3) & 7, dz = n1 & 7;
    int n = ((2 * ho + ((kk >> 2) & 1)) << 8) + ((2 * wo + ((kk >> 1) & 1)) << 4) + (2 * dz + (kk & 1));
    A1[gid] = xa[((size_t)b * 4096 + n) * 384 + ci];
}

// ---------- LayerNorm (+ optional GELU); C = 384, 128 threads, 1 block/row ----------
__global__ __launch_bounds__(128) void ln_kernel(const float* __restrict__ in,
                                                 const float* __restrict__ w,
                                                 const float* __restrict__ b,
                                                 float* __restrict__ outf,
                                                 ushort_t* __restrict__ outb, int act) {
    const int C = 384;
    int row = blockIdx.x, tid = threadIdx.x;
    size_t base = (size_t)row * C;
    float x[3], s = 0.f, s2 = 0.f;
#pragma unroll
    for (int i = 0; i < 3; i++) {
        int c = tid + i * 128;
        float v = in[base + c];
        x[i] = v; s += v; s2 += v * v;
    }
    for (int off = 32; off; off >>= 1) { s += __shfl_down(s, off); s2 += __shfl_down(s2, off); }
    __shared__ float sc[4];
    int lane = tid & 63, wid = tid >> 6;
    if (lane == 0) { sc[wid] = s; sc[wid + 2] = s2; }
    __syncthreads();
    float ts = sc[0] + sc[1], ts2 = sc[2] + sc[3];
    float mean = ts / C;
    float var = ts2 / C - mean * mean;
    float rstd = rsqrtf(var + 1e-5f);
#pragma unroll
    for (int i = 0; i < 3; i++) {
        int c = tid + i * 128;
        float v = (x[i] - mean) * rstd * w[c] + b[c];
        if (act) v = gelu_exact(v);
        if (outf) outf[base + c] = v;
        if (outb) outb[base + c] = f2b(v);
    }
}

// ---------- MFMA GEMM: C[M,N] = act(A[M,K] @ W[N,K]^T + bias) (+res) ----------
// A,W bf16. 128x128 tile, BK=32, 4 waves in 2x2 grid, 4x4 fragments of 16x16x32.
__global__ __launch_bounds__(256) void mfma_gemm(const ushort_t* __restrict__ A,
                                                 const ushort_t* __restrict__ W,
                                                 const float* __restrict__ bias,
                                                 const float* __restrict__ res,
                                                 float* __restrict__ outf,
                                                 ushort_t* __restrict__ outb,
                                                 int M, int N, int K, int act) {
    __shared__ bf16_t Asl[128][40];   // 80B row pitch: starts spread over 8 banks
    __shared__ bf16_t Wsl[128][40];
    int tid = threadIdx.x;
    int wave = tid >> 6, lane = tid & 63, g = lane >> 4, c = lane & 15;
    int wm = wave >> 1, wn = wave & 1;
    int m0 = blockIdx.y * 128, n0 = blockIdx.x * 128;
    int srow = tid >> 1, sseg = tid & 1;   // staging: row 0..127, 16-elem segment

    f32x4 acc[4][4];
#pragma unroll
    for (int i = 0; i < 4; i++)
#pragma unroll
        for (int j = 0; j < 4; j++) acc[i][j] = f32x4{0.f, 0.f, 0.f, 0.f};

    for (int k0 = 0; k0 < K; k0 += 32) {
        const ushort_t* As = A + (size_t)(m0 + srow) * K + k0 + sseg * 16;
        const ushort_t* Ws = W + (size_t)(n0 + srow) * K + k0 + sseg * 16;
        uint4 av0 = *(const uint4*)As, av1 = *(const uint4*)(As + 8);
        uint4 wv0 = *(const uint4*)Ws, wv1 = *(const uint4*)(Ws + 8);
        __syncthreads();
        *(uint4*)&Asl[srow][sseg * 16] = av0;
        *(uint4*)&Asl[srow][sseg * 16 + 8] = av1;
        *(uint4*)&Wsl[srow][sseg * 16] = wv0;
        *(uint4*)&Wsl[srow][sseg * 16 + 8] = wv1;
        __syncthreads();
        bf16x8 af[4], bf[4];
#pragma unroll
        for (int fi = 0; fi < 4; fi++) af[fi] = *(bf16x8*)&Asl[wm * 64 + fi * 16 + c][g * 8];
#pragma unroll
        for (int fj = 0; fj < 4; fj++) bf[fj] = *(bf16x8*)&Wsl[wn * 64 + fj * 16 + c][g * 8];
#pragma unroll
        for (int fi = 0; fi < 4; fi++)
#pragma unroll
            for (int fj = 0; fj < 4; fj++)
                acc[fi][fj] = __builtin_amdgcn_mfma_f32_16x16x32_bf16(af[fi], bf[fj], acc[fi][fj], 0, 0, 0);
    }

#pragma unroll
    for (int fi = 0; fi < 4; fi++) {
#pragma unroll
        for (int fj = 0; fj < 4; fj++) {
            int n = n0 + wn * 64 + fj * 16 + c;
            float bv = bias ? bias[n] : 0.f;
#pragma unroll
            for (int i = 0; i < 4; i++) {
                int m = m0 + wm * 64 + fi * 16 + 4 * g + i;
                float v = acc[fi][fj][i] + bv;
                if (act == 1) v = gelu_exact(v);
                size_t idx = (size_t)m * N + n;
                if (res) v += res[idx];
                if (outf) outf[idx] = v;
                if (outb) outb[idx] = f2b(v);
            }
        }
    }
}

// ---------- depthwise 3x3x3 SAME residual conv on V ----------
__global__ void dwconv_kernel(const ushort_t* __restrict__ vin,
                              const float* __restrict__ wt,
                              const float* __restrict__ bias,
                              ushort_t* __restrict__ vout,
                              int Hs, int Wsz, int Ds, int S, int total) {
    int gid = blockIdx.x * 256 + threadIdx.x;
    if (gid >= total) return;
    int c2 = gid % 192;
    int r = gid / 192;
    int n = r % S;
    int b = r / S;
    int dz = n % Ds, wy = (n / Ds) % Wsz, hx = n / (Wsz * Ds);
    float center = b2f(vin[(size_t)(b * S + n) * 384 + c2]);
    float acc = bias[c2];
    for (int kh = -1; kh <= 1; kh++) {
        int h2 = hx + kh; if (h2 < 0 || h2 >= Hs) continue;
        for (int kw = -1; kw <= 1; kw++) {
            int w2 = wy + kw; if (w2 < 0 || w2 >= Wsz) continue;
            for (int kd = -1; kd <= 1; kd++) {
                int d2 = dz + kd; if (d2 < 0 || d2 >= Ds) continue;
                int nn = (h2 * Wsz + w2) * Ds + d2;
                acc += b2f(vin[(size_t)(b * S + nn) * 384 + c2]) *
                       wt[c2 * 27 + (kh + 1) * 9 + (kw + 1) * 3 + (kd + 1)];
            }
        }
    }
    vout[(size_t)(b * S + n) * 192 + c2] = f2b(center + acc);
}

// ---------- MFMA flash attention (64 q-rows/block, 4 waves, KBLK=64) ----------
__global__ __launch_bounds__(256) void attn_mfma_kernel(
    const ushort_t* __restrict__ qbuf,
    const ushort_t* __restrict__ kvbuf,
    const ushort_t* __restrict__ vbuf,
    ushort_t* __restrict__ obuf,
    int NK, int head_base, int out_base)
{
    __shared__ bf16_t Q_lds[64][72];
    __shared__ bf16_t K_lds[64][72];
    __shared__ bf16_t VT_lds[48][72];
    __shared__ bf16_t P_lds[64][72];

    const int N = 4096;
    int tid = threadIdx.x;
    int q0 = blockIdx.x * 64, hl = blockIdx.y, b = blockIdx.z;
    int wave = tid >> 6, lane = tid & 63, g = lane >> 4, c = lane & 15;
    const float scale = 0.14433756729740643f;  // 48^-0.5

    {
        const ushort_t* qsrc = qbuf + ((size_t)b * N + q0) * 384 + (head_base + hl) * 48;
        for (int u = tid; u < 1536; u += 256) {
            int r = u / 24, cp = u % 24;
            *(uint_t*)&Q_lds[r][cp * 2] = *(const uint_t*)(qsrc + (size_t)r * 384 + cp * 2);
        }
        for (int u = tid; u < 512; u += 256) {
            int r = u / 8, cp = u % 8;
            *(uint_t*)&Q_lds[r][48 + cp * 2] = 0;
        }
    }

    f32x4 of[3];
#pragma unroll
    for (int dt = 0; dt < 3; dt++) of[dt] = f32x4{0.f, 0.f, 0.f, 0.f};
    float m_run[4] = {-1e30f, -1e30f, -1e30f, -1e30f};
    float l_run[4] = {0.f, 0.f, 0.f, 0.f};

    const ushort_t* ksrc0 = kvbuf + (size_t)b * NK * 384 + hl * 48;
    const ushort_t* vsrc0 = vbuf + (size_t)b * NK * 192 + hl * 48;
    int nkt = NK >> 6;

    for (int kt = 0; kt < nkt; kt++) {
        __syncthreads();
        const ushort_t* ksrc = ksrc0 + (size_t)kt * 64 * 384;
        for (int u = tid; u < 1536; u += 256) {
            int r = u / 24, cp = u % 24;
            *(uint_t*)&K_lds[r][cp * 2] = *(const uint_t*)(ksrc + (size_t)r * 384 + cp * 2);
        }
        for (int u = tid; u < 512; u += 256) {
            int r = u / 8, cp = u % 8;
            *(uint_t*)&K_lds[r][48 + cp * 2] = 0;
        }
        const ushort_t* vsrc = vsrc0 + (size_t)kt * 64 * 192;
        for (int u = tid; u < 1536; u += 256) {
            int j = u / 24, dp = u % 24;
            uint_t val = *(const uint_t*)(vsrc + (size_t)j * 192 + dp * 2);
            *(ushort_t*)&VT_lds[dp * 2 + 0][j] = (ushort_t)(val & 0xffffu);
            *(ushort_t*)&VT_lds[dp * 2 + 1][j] = (ushort_t)(val >> 16);
        }
        __syncthreads();

        f32x4 sf[4];
#pragma unroll
        for (int t = 0; t < 4; t++) sf[t] = f32x4{0.f, 0.f, 0.f, 0.f};
        bf16x8 aq0 = *(bf16x8*)&Q_lds[16 * wave + c][g * 8];
        bf16x8 aq1 = *(bf16x8*)&Q_lds[16 * wave + c][32 + g * 8];
#pragma unroll
        for (int t = 0; t < 4; t++) {
            bf16x8 bk0 = *(bf16x8*)&K_lds[16 * t + c][g * 8];
            bf16x8 bk1 = *(bf16x8*)&K_lds[16 * t + c][32 + g * 8];
            sf[t] = __builtin_amdgcn_mfma_f32_16x16x32_bf16(aq0, bk0, sf[t], 0, 0, 0);
            sf[t] = __builtin_amdgcn_mfma_f32_16x16x32_bf16(aq1, bk1, sf[t], 0, 0, 0);
        }

        float mx[4];
#pragma unroll
        for (int i = 0; i < 4; i++)
            mx[i] = fmaxf(fmaxf(sf[0][i], sf[1][i]), fmaxf(sf[2][i], sf[3][i])) * scale;
#pragma unroll
        for (int m = 1; m < 16; m <<= 1) {
#pragma unroll
            for (int i = 0; i < 4; i++) mx[i] = fmaxf(mx[i], __shfl_xor(mx[i], m));
        }
        float fct[4];
#pragma unroll
        for (int i = 0; i < 4; i++) {
            float mn = fmaxf(m_run[i], mx[i]);
            fct[i] = __expf(m_run[i] - mn);
            m_run[i] = mn;
        }
        float rs[4] = {0.f, 0.f, 0.f, 0.f};
#pragma unroll
        for (int t = 0; t < 4; t++) {
#pragma unroll
            for (int i = 0; i < 4; i++) {
                float p = __expf(sf[t][i] * scale - m_run[i]);
                rs[i] += p;
                P_lds[16 * wave + 4 * g + i][16 * t + c] = (bf16_t)p;
            }
        }
#pragma unroll
        for (int m = 1; m < 16; m <<= 1) {
#pragma unroll
            for (int i = 0; i < 4; i++) rs[i] += __shfl_xor(rs[i], m);
        }
#pragma unroll
        for (int i = 0; i < 4; i++) l_run[i] = l_run[i] * fct[i] + rs[i];
#pragma unroll
        for (int dt = 0; dt < 3; dt++) {
#pragma unroll
            for (int i = 0; i < 4; i++) of[dt][i] *= fct[i];
        }
        __syncthreads();

        bf16x8 pa0 = *(bf16x8*)&P_lds[16 * wave + c][g * 8];
        bf16x8 pa1 = *(bf16x8*)&P_lds[16 * wave + c][32 + g * 8];
#pragma unroll
        for (int dt = 0; dt < 3; dt++) {
            bf16x8 v0 = *(bf16x8*)&VT_lds[dt * 16 + c][g * 8];
            bf16x8 v1 = *(bf16x8*)&VT_lds[dt * 16 + c][32 + g * 8];
            of[dt] = __builtin_amdgcn_mfma_f32_16x16x32_bf16(pa0, v0, of[dt], 0, 0, 0);
            of[dt] = __builtin_amdgcn_mfma_f32_16x16x32_bf16(pa1, v1, of[dt], 0, 0, 0);
        }
    }

#pragma unroll
    for (int dt = 0; dt < 3; dt++) {
#pragma unroll
        for (int i = 0; i < 4; i++) {
            int row = q0 + 16 * wave + 4 * g + i;
            int col = out_base + hl * 48 + dt * 16 + c;
            obuf[((size_t)b * N + row) * 384 + col] = f2b(of[dt][i] / l_run[i]);
        }
    }
}

// ---------- host ----------
extern "C" void kernel_launch(void* const* d_in, const int* in_sizes, int n_in,
                              void* d_out, int out_size, void* d_ws, size_t ws_size,
                              hipStream_t stream) {
    const int B = 2, N = 4096, C = 384, N1 = 512, HID = 1536;
    const float* x      = (const float*)d_in[0];
    const float* ln1_w  = (const float*)d_in[1];
    const float* ln1_b  = (const float*)d_in[2];
    const float* q_w    = (const float*)d_in[3];
    const float* sr1_w  = (const float*)d_in[4];
    const float* sr1_b  = (const float*)d_in[5];
    const float* n1_w   = (const float*)d_in[6];
    const float* n1_b   = (const float*)d_in[7];
    const float* sr2_w  = (const float*)d_in[8];
    const float* sr2_b  = (const float*)d_in[9];
    const float* n2_w   = (const float*)d_in[10];
    const float* n2_b   = (const float*)d_in[11];
    const float* kv1_w  = (const float*)d_in[12];
    const float* kv2_w  = (const float*)d_in[13];
    const float* lc1_w  = (const float*)d_in[14];
    const float* lc1_b  = (const float*)d_in[15];
    const float* lc2_w  = (const float*)d_in[16];
    const float* lc2_b  = (const float*)d_in[17];
    const float* proj_w = (const float*)d_in[18];
    const float* proj_b = (const float*)d_in[19];
    const float* ln2_w  = (const float*)d_in[20];
    const float* ln2_b  = (const float*)d_in[21];
    const float* fc1_w  = (const float*)d_in[22];
    const float* fc1_b  = (const float*)d_in[23];
    const float* fc2_w  = (const float*)d_in[24];
    const float* fc2_b  = (const float*)d_in[25];
    float* out = (float*)d_out;

    char* ws = (char*)d_ws;
    // bf16 weight arena
    ushort_t* wq   = (ushort_t*)(ws + 0);          // 147456 el
    ushort_t* wsr2 = (ushort_t*)(ws + 294912);
    ushort_t* wkv1 = (ushort_t*)(ws + 589824);
    ushort_t* wkv2 = (ushort_t*)(ws + 884736);
    ushort_t* wproj= (ushort_t*)(ws + 1179648);
    ushort_t* wfc1 = (ushort_t*)(ws + 1474560);    // 589824 el
    ushort_t* wfc2 = (ushort_t*)(ws + 2654208);
    ushort_t* wsr1 = (ushort_t*)(ws + 3833856);    // 1179648 el -> end 6193152
    // activations
    ushort_t* xa_bf = (ushort_t*)(ws + 6193152);   // [8192][384] bf16; later Obuf
    ushort_t* qbB   = (ushort_t*)(ws + 12484608);  // [8192][384] bf16
    ushort_t* x2_bf = (ushort_t*)(ws + 18776064);  // [8192][384] bf16
    ushort_t* kv2   = (ushort_t*)(ws + 25067520);  // [8192][384] bf16
    ushort_t* vmod2 = (ushort_t*)(ws + 31358976);  // [8192][192] bf16
    ushort_t* kv1   = (ushort_t*)(ws + 34504704);  // [1024][384] bf16
    ushort_t* vmod1 = (ushort_t*)(ws + 35291136);  // [1024][192] bf16
    ushort_t* x1_bf = (ushort_t*)(ws + 35684352);  // [1024][384] bf16
    float*    y2f   = (float*)(ws + 36470784);     // [8192][384] f32; later xres
    float*    y1f   = (float*)(ws + 49053696);     // [1024][384] f32
    ushort_t* A1    = (ushort_t*)(ws + 50626560);  // [1024][3072] bf16; later xm_bf
    ushort_t* hid   = (ushort_t*)(ws + 56918016);  // [8192][1536] bf16 -> end 82083840
    ushort_t* Obuf  = xa_bf;
    float*    xres  = y2f;
    ushort_t* xm_bf = A1;

    // 0. weight conversion (bf16)
    cvt_kernel<<<(147456 + 255) / 256, 256, 0, stream>>>(q_w,   wq,   147456);
    cvt_kernel<<<(147456 + 255) / 256, 256, 0, stream>>>(sr2_w, wsr2, 147456);
    cvt_kernel<<<(147456 + 255) / 256, 256, 0, stream>>>(kv1_w, wkv1, 147456);
    cvt_kernel<<<(147456 + 255) / 256, 256, 0, stream>>>(kv2_w, wkv2, 147456);
    cvt_kernel<<<(147456 + 255) / 256, 256, 0, stream>>>(proj_w, wproj, 147456);
    cvt_kernel<<<(589824 + 255) / 256, 256, 0, stream>>>(fc1_w, wfc1, 589824);
    cvt_kernel<<<(589824 + 255) / 256, 256, 0, stream>>>(fc2_w, wfc2, 589824);
    sr1w_kernel<<<(1179648 + 255) / 256, 256, 0, stream>>>(sr1_w, wsr1, 1179648);

    // 1. xa = LN(x) -> bf16
    ln_kernel<<<B * N, 128, 0, stream>>>(x, ln1_w, ln1_b, nullptr, xa_bf, 0);
    // 2. q = xa @ q_w^T (bf16 out)
    mfma_gemm<<<dim3(3, 64), 256, 0, stream>>>(xa_bf, wq, nullptr, nullptr,
                                               nullptr, qbB, B * N, C, C, 0);
    // 3. y2 = xa @ sr2_w^T + b (f32 out)
    mfma_gemm<<<dim3(3, 64), 256, 0, stream>>>(xa_bf, wsr2, sr2_b, nullptr,
                                               y2f, nullptr, B * N, C, C, 0);
    // 4. x2 = gelu(LN(y2)) -> bf16
    ln_kernel<<<B * N, 128, 0, stream>>>(y2f, n2_w, n2_b, nullptr, x2_bf, 1);
    // 5. im2col + sr1 GEMM: y1 = A1 @ wsr1^T + sr1_b
    im2col_kernel<<<(1024 * 3072 + 255) / 256, 256, 0, stream>>>(xa_bf, A1);
    mfma_gemm<<<dim3(3, 8), 256, 0, stream>>>(A1, wsr1, sr1_b, nullptr,
                                              y1f, nullptr, 1024, C, 3072, 0);
    // 6. x1 = gelu(LN(y1)) -> bf16
    ln_kernel<<<B * N1, 128, 0, stream>>>(y1f, n1_w, n1_b, nullptr, x1_bf, 1);
    // 7. kv2 = x2 @ kv2_w^T (bf16 out)
    mfma_gemm<<<dim3(3, 64), 256, 0, stream>>>(x2_bf, wkv2, nullptr, nullptr,
                                               nullptr, kv2, B * N, C, C, 0);
    // 8. kv1 = x1 @ kv1_w^T (bf16 out)
    mfma_gemm<<<dim3(3, 8), 256, 0, stream>>>(x1_bf, wkv1, nullptr, nullptr,
                                              nullptr, kv1, 1024, C, C, 0);
    // 9/10. vmod = v + dwconv3(v)
    {
        int total2 = B * N * 192;
        dwconv_kernel<<<(total2 + 255) / 256, 256, 0, stream>>>(kv2 + 192, lc2_w, lc2_b, vmod2,
                                                                16, 16, 16, N, total2);
        int total1 = B * N1 * 192;
        dwconv_kernel<<<(total1 + 255) / 256, 256, 0, stream>>>(kv1 + 192, lc1_w, lc1_b, vmod1,
                                                                8, 8, 8, N1, total1);
    }
    // 11. attention branch1 (NK=512, heads 0-3 -> out ch 0-191)
    attn_mfma_kernel<<<dim3(N / 64, 4, B), 256, 0, stream>>>(qbB, kv1, vmod1, Obuf, 512, 0, 0);
    // 12. attention branch2 (NK=4096, heads 4-7 -> out ch 192-383)
    attn_mfma_kernel<<<dim3(N / 64, 4, B), 256, 0, stream>>>(qbB, kv2, vmod2, Obuf, 4096, 4, 192);
    // 13. xres = x + O @ proj_w^T + proj_b (f32)
    mfma_gemm<<<dim3(3, 64), 256, 0, stream>>>(Obuf, wproj, proj_b, x,
                                               xres, nullptr, B * N, C, C, 0);
    // 14. xm = LN(xres) -> bf16
    ln_kernel<<<B * N, 128, 0, stream>>>(xres, ln2_w, ln2_b, nullptr, xm_bf, 0);
    // 15. hid = gelu(xm @ fc1^T + b) (bf16 out)
    mfma_gemm<<<dim3(12, 64), 256, 0, stream>>>(xm_bf, wfc1, fc1_b, nullptr,
                                                nullptr, hid, B * N, HID, C, 1);
    // 16. out = xres + hid @ fc2^T + b (f32 -> d_out)
    mfma_gemm<<<dim3(3, 64), 256, 0, stream>>>(hid, wfc2, fc2_b, xres,
                                               out, nullptr, B * N, C, HID, 0);
}

// Round 7
// 673.686 us; speedup vs baseline: 6.6536x; 1.0657x over previous
//
#include <hip/hip_runtime.h>

typedef unsigned short ushort_t;
typedef unsigned int uint_t;
typedef __bf16 bf16_t;
typedef __bf16 bf16x8 __attribute__((ext_vector_type(8)));
typedef float f32x4 __attribute__((ext_vector_type(4)));

// ---------- helpers ----------
__device__ __forceinline__ float b2f(ushort_t u) {
    union { uint_t i; float f; } v; v.i = ((uint_t)u) << 16; return v.f;
}
__device__ __forceinline__ ushort_t f2b(float f) {
    union { float f; uint_t i; } v; v.f = f;
    uint_t r = v.i + 0x7fffu + ((v.i >> 16) & 1u);
    return (ushort_t)(r >> 16);
}
__device__ __forceinline__ float gelu_exact(float x) {
    return 0.5f * x * (1.0f + erff(x * 0.70710678118654752f));
}

// ---------- f32 -> bf16 convert ----------
__global__ void cvt_kernel(const float* __restrict__ src, ushort_t* __restrict__ dst, int n) {
    int i = blockIdx.x * 256 + threadIdx.x;
    if (i < n) dst[i] = f2b(src[i]);
}

// ---------- sr1 weight reorder: w[co][ci][kk] -> w2[co][kk*384+ci] (bf16) ----------
__global__ void sr1w_kernel(const float* __restrict__ src, ushort_t* __restrict__ dst, int n) {
    int gid = blockIdx.x * 256 + threadIdx.x;
    if (gid >= n) return;
    int co = gid / 3072, r = gid % 3072, kk = r / 384, ci = r % 384;
    dst[gid] = f2b(src[((size_t)co * 384 + ci) * 8 + kk]);
}

// ---------- im2col for sr1 ----------
__global__ void im2col_kernel(const ushort_t* __restrict__ xa, ushort_t* __restrict__ A1) {
    int gid = blockIdx.x * 256 + threadIdx.x;
    if (gid >= 1024 * 3072) return;
    int m = gid / 3072, r = gid % 3072, kk = r / 384, ci = r % 384;
    int b = m >> 9, n1 = m & 511;
    int ho = n1 >> 6, wo = (n1 >> 3) & 7, dz = n1 & 7;
    int n = ((2 * ho + ((kk >> 2) & 1)) << 8) + ((2 * wo + ((kk >> 1) & 1)) << 4) + (2 * dz + (kk & 1));
    A1[gid] = xa[((size_t)b * 4096 + n) * 384 + ci];
}

// ---------- LayerNorm (+ optional GELU); C = 384 ----------
__global__ __launch_bounds__(128) void ln_kernel(const float* __restrict__ in,
                                                 const float* __restrict__ w,
                                                 const float* __restrict__ b,
                                                 float* __restrict__ outf,
                                                 ushort_t* __restrict__ outb, int act) {
    const int C = 384;
    int row = blockIdx.x, tid = threadIdx.x;
    size_t base = (size_t)row * C;
    float x[3], s = 0.f, s2 = 0.f;
#pragma unroll
    for (int i = 0; i < 3; i++) {
        int c = tid + i * 128;
        float v = in[base + c];
        x[i] = v; s += v; s2 += v * v;
    }
    for (int off = 32; off; off >>= 1) { s += __shfl_down(s, off); s2 += __shfl_down(s2, off); }
    __shared__ float sc[4];
    int lane = tid & 63, wid = tid >> 6;
    if (lane == 0) { sc[wid] = s; sc[wid + 2] = s2; }
    __syncthreads();
    float ts = sc[0] + sc[1], ts2 = sc[2] + sc[3];
    float mean = ts / C;
    float var = ts2 / C - mean * mean;
    float rstd = rsqrtf(var + 1e-5f);
#pragma unroll
    for (int i = 0; i < 3; i++) {
        int c = tid + i * 128;
        float v = (x[i] - mean) * rstd * w[c] + b[c];
        if (act) v = gelu_exact(v);
        if (outf) outf[base + c] = v;
        if (outb) outb[base + c] = f2b(v);
    }
}

// ---------- MFMA GEMM: C = act(A @ W^T + bias) (+res). 128x128 tile, BK=32 ----------
__global__ __launch_bounds__(256) void mfma_gemm(const ushort_t* __restrict__ A,
                                                 const ushort_t* __restrict__ W,
                                                 const float* __restrict__ bias,
                                                 const float* __restrict__ res,
                                                 float* __restrict__ outf,
                                                 ushort_t* __restrict__ outb,
                                                 int M, int N, int K, int act) {
    __shared__ bf16_t Asl[128][40];
    __shared__ bf16_t Wsl[128][40];
    int tid = threadIdx.x;
    int wave = tid >> 6, lane = tid & 63, g = lane >> 4, c = lane & 15;
    int wm = wave >> 1, wn = wave & 1;
    int m0 = blockIdx.y * 128, n0 = blockIdx.x * 128;
    int srow = tid >> 1, sseg = tid & 1;

    f32x4 acc[4][4];
#pragma unroll
    for (int i = 0; i < 4; i++)
#pragma unroll
        for (int j = 0; j < 4; j++) acc[i][j] = f32x4{0.f, 0.f, 0.f, 0.f};

    for (int k0 = 0; k0 < K; k0 += 32) {
        const ushort_t* As = A + (size_t)(m0 + srow) * K + k0 + sseg * 16;
        const ushort_t* Ws = W + (size_t)(n0 + srow) * K + k0 + sseg * 16;
        uint4 av0 = *(const uint4*)As, av1 = *(const uint4*)(As + 8);
        uint4 wv0 = *(const uint4*)Ws, wv1 = *(const uint4*)(Ws + 8);
        __syncthreads();
        *(uint4*)&Asl[srow][sseg * 16] = av0;
        *(uint4*)&Asl[srow][sseg * 16 + 8] = av1;
        *(uint4*)&Wsl[srow][sseg * 16] = wv0;
        *(uint4*)&Wsl[srow][sseg * 16 + 8] = wv1;
        __syncthreads();
        bf16x8 af[4], bf[4];
#pragma unroll
        for (int fi = 0; fi < 4; fi++) af[fi] = *(bf16x8*)&Asl[wm * 64 + fi * 16 + c][g * 8];
#pragma unroll
        for (int fj = 0; fj < 4; fj++) bf[fj] = *(bf16x8*)&Wsl[wn * 64 + fj * 16 + c][g * 8];
#pragma unroll
        for (int fi = 0; fi < 4; fi++)
#pragma unroll
            for (int fj = 0; fj < 4; fj++)
                acc[fi][fj] = __builtin_amdgcn_mfma_f32_16x16x32_bf16(af[fi], bf[fj], acc[fi][fj], 0, 0, 0);
    }

#pragma unroll
    for (int fi = 0; fi < 4; fi++) {
#pragma unroll
        for (int fj = 0; fj < 4; fj++) {
            int n = n0 + wn * 64 + fj * 16 + c;
            float bv = bias ? bias[n] : 0.f;
#pragma unroll
            for (int i = 0; i < 4; i++) {
                int m = m0 + wm * 64 + fi * 16 + 4 * g + i;
                float v = acc[fi][fj][i] + bv;
                if (act == 1) v = gelu_exact(v);
                size_t idx = (size_t)m * N + n;
                if (res) v += res[idx];
                if (outf) outf[idx] = v;
                if (outb) outb[idx] = f2b(v);
            }
        }
    }
}

// ---------- depthwise 3x3x3 SAME residual conv on V ----------
__global__ void dwconv_kernel(const ushort_t* __restrict__ vin,
                              const float* __restrict__ wt,
                              const float* __restrict__ bias,
                              ushort_t* __restrict__ vout,
                              int Hs, int Wsz, int Ds, int S, int total) {
    int gid = blockIdx.x * 256 + threadIdx.x;
    if (gid >= total) return;
    int c2 = gid % 192;
    int r = gid / 192;
    int n = r % S;
    int b = r / S;
    int dz = n % Ds, wy = (n / Ds) % Wsz, hx = n / (Wsz * Ds);
    float center = b2f(vin[(size_t)(b * S + n) * 384 + c2]);
    float acc = bias[c2];
    for (int kh = -1; kh <= 1; kh++) {
        int h2 = hx + kh; if (h2 < 0 || h2 >= Hs) continue;
        for (int kw = -1; kw <= 1; kw++) {
            int w2 = wy + kw; if (w2 < 0 || w2 >= Wsz) continue;
            for (int kd = -1; kd <= 1; kd++) {
                int d2 = dz + kd; if (d2 < 0 || d2 >= Ds) continue;
                int nn = (h2 * Wsz + w2) * Ds + d2;
                acc += b2f(vin[(size_t)(b * S + nn) * 384 + c2]) *
                       wt[c2 * 27 + (kh + 1) * 9 + (kw + 1) * 3 + (kd + 1)];
            }
        }
    }
    vout[(size_t)(b * S + n) * 192 + c2] = f2b(center + acc);
}

// ---------- transpose vmod [b][S][192] -> vt [b][192][S] ----------
__global__ __launch_bounds__(256) void transpose_kernel(const ushort_t* __restrict__ src,
                                                        ushort_t* __restrict__ dst, int S) {
    __shared__ ushort_t t_lds[64][65];
    int n0 = blockIdx.x * 64, c0 = blockIdx.y * 64, b = blockIdx.z;
    int tid = threadIdx.x;
#pragma unroll
    for (int i = 0; i < 16; i++) {
        int idx = tid + i * 256;
        int r = idx >> 6, cc = idx & 63;
        t_lds[r][cc] = src[((size_t)b * S + n0 + r) * 192 + c0 + cc];
    }
    __syncthreads();
#pragma unroll
    for (int i = 0; i < 16; i++) {
        int idx = tid + i * 256;
        int r = idx >> 6, cc = idx & 63;
        dst[((size_t)b * 192 + c0 + r) * S + n0 + cc] = t_lds[cc][r];
    }
}

// ---------- MFMA flash attention, swapped-operand, both branches merged ----------
// hl 0..3: NK=512 (kv1/vt1); hl 4..7: NK=4096 (kv2/vt2). q/o ch = hl*48, kv/vt ch = (hl&3)*48.
__global__ __launch_bounds__(256) void attn_mfma2(
    const ushort_t* __restrict__ qbuf,
    const ushort_t* __restrict__ kv1,
    const ushort_t* __restrict__ kv2,
    const ushort_t* __restrict__ vt1,
    const ushort_t* __restrict__ vt2,
    ushort_t* __restrict__ obuf)
{
    __shared__ bf16_t Q_lds[64][72];
    __shared__ bf16_t K_lds[64][72];
    __shared__ bf16_t VT_lds[48][72];
    __shared__ bf16_t P_lds[64][72];

    const int N = 4096;
    int tid = threadIdx.x;
    int q0 = blockIdx.x * 64, hl = blockIdx.y, b = blockIdx.z;
    int wave = tid >> 6, lane = tid & 63, g = lane >> 4, c = lane & 15;
    const float scale = 0.14433756729740643f;  // 48^-0.5
    int br2 = hl >> 2;
    int NK = br2 ? 4096 : 512;
    const ushort_t* kbuf = br2 ? kv2 : kv1;
    const ushort_t* vtb  = br2 ? vt2 : vt1;
    int hloc = hl & 3;

    // ---- stage Q tile once: 64 rows x 48 + zero-pad to 64 ----
    {
        const ushort_t* qsrc = qbuf + ((size_t)b * N + q0) * 384 + hl * 48;
        for (int u = tid; u < 1536; u += 256) {
            int r = u / 24, cp = u % 24;
            *(uint_t*)&Q_lds[r][cp * 2] = *(const uint_t*)(qsrc + (size_t)r * 384 + cp * 2);
        }
        for (int u = tid; u < 512; u += 256) {
            int r = u >> 3, cp = u & 7;
            *(uint_t*)&Q_lds[r][48 + cp * 2] = 0;
        }
    }

    f32x4 of[3];
#pragma unroll
    for (int dt = 0; dt < 3; dt++) of[dt] = f32x4{0.f, 0.f, 0.f, 0.f};
    float m_run = -1e30f, l_run = 0.f;

    const ushort_t* ksrc0 = kbuf + (size_t)b * NK * 384 + hloc * 48;
    const ushort_t* vsrc0 = vtb + ((size_t)b * 192 + hloc * 48) * NK;
    int nkt = NK >> 6;

    for (int kt = 0; kt < nkt; kt++) {
        __syncthreads();   // prev tile's reads done before overwrite
        // ---- stage K tile [64][48] + zero-pad ----
        const ushort_t* ksrc = ksrc0 + (size_t)kt * 64 * 384;
        for (int u = tid; u < 1536; u += 256) {
            int r = u / 24, cp = u % 24;
            *(uint_t*)&K_lds[r][cp * 2] = *(const uint_t*)(ksrc + (size_t)r * 384 + cp * 2);
        }
        for (int u = tid; u < 512; u += 256) {
            int r = u >> 3, cp = u & 7;
            *(uint_t*)&K_lds[r][48 + cp * 2] = 0;
        }
        // ---- stage VT tile [48][64] from pre-transposed global (linear dwords) ----
        for (int u = tid; u < 1536; u += 256) {
            int d = u >> 5, k2 = u & 31;
            *(uint_t*)&VT_lds[d][k2 * 2] =
                *(const uint_t*)(vsrc0 + (size_t)d * NK + kt * 64 + k2 * 2);
        }
        __syncthreads();

        // ---- S^T = K Q^T: sf[t] rows key=16t+4g+i, col qrow=c (of wave's 16 rows) ----
        f32x4 sf[4];
#pragma unroll
        for (int t = 0; t < 4; t++) sf[t] = f32x4{0.f, 0.f, 0.f, 0.f};
        bf16x8 bq0 = *(bf16x8*)&Q_lds[16 * wave + c][g * 8];
        bf16x8 bq1 = *(bf16x8*)&Q_lds[16 * wave + c][32 + g * 8];
#pragma unroll
        for (int t = 0; t < 4; t++) {
            bf16x8 ak0 = *(bf16x8*)&K_lds[16 * t + c][g * 8];
            bf16x8 ak1 = *(bf16x8*)&K_lds[16 * t + c][32 + g * 8];
            sf[t] = __builtin_amdgcn_mfma_f32_16x16x32_bf16(ak0, bq0, sf[t], 0, 0, 0);
            sf[t] = __builtin_amdgcn_mfma_f32_16x16x32_bf16(ak1, bq1, sf[t], 0, 0, 0);
        }

        // ---- online softmax: lane owns q-row c; combine g-groups via xor16/32 ----
        float mx = -1e30f;
#pragma unroll
        for (int t = 0; t < 4; t++)
#pragma unroll
            for (int i = 0; i < 4; i++) mx = fmaxf(mx, sf[t][i]);
        mx *= scale;
        mx = fmaxf(mx, __shfl_xor(mx, 16));
        mx = fmaxf(mx, __shfl_xor(mx, 32));
        float mn = fmaxf(m_run, mx);
        float fct = __expf(m_run - mn);
        m_run = mn;
        float rs = 0.f;
#pragma unroll
        for (int t = 0; t < 4; t++) {
            union { ushort4 v; bf16_t h[4]; } pk;
#pragma unroll
            for (int i = 0; i < 4; i++) {
                float p = __expf(sf[t][i] * scale - mn);
                rs += p;
                pk.h[i] = (bf16_t)p;
            }
            *(ushort4*)&P_lds[16 * wave + c][16 * t + 4 * g] = pk.v;
        }
        rs += __shfl_xor(rs, 16);
        rs += __shfl_xor(rs, 32);
        l_run = l_run * fct + rs;
#pragma unroll
        for (int dt = 0; dt < 3; dt++)
#pragma unroll
            for (int i = 0; i < 4; i++) of[dt][i] *= fct;

        // wave-local P write->read ordering fence
        asm volatile("s_waitcnt lgkmcnt(0)" ::: "memory");

        // ---- O^T += VT P^T: of[dt] rows d=16dt+4g+i, col qrow=c ----
        bf16x8 pb0 = *(bf16x8*)&P_lds[16 * wave + c][g * 8];
        bf16x8 pb1 = *(bf16x8*)&P_lds[16 * wave + c][32 + g * 8];
#pragma unroll
        for (int dt = 0; dt < 3; dt++) {
            bf16x8 av0 = *(bf16x8*)&VT_lds[16 * dt + c][g * 8];
            bf16x8 av1 = *(bf16x8*)&VT_lds[16 * dt + c][32 + g * 8];
            of[dt] = __builtin_amdgcn_mfma_f32_16x16x32_bf16(av0, pb0, of[dt], 0, 0, 0);
            of[dt] = __builtin_amdgcn_mfma_f32_16x16x32_bf16(av1, pb1, of[dt], 0, 0, 0);
        }
    }

    // ---- epilogue: lane owns q-row, 4 consecutive d per (dt) -> b64 stores ----
    float rl = 1.f / l_run;
    int qrow = q0 + 16 * wave + c;
#pragma unroll
    for (int dt = 0; dt < 3; dt++) {
        union { ushort4 v; bf16_t h[4]; } pk;
#pragma unroll
        for (int i = 0; i < 4; i++) pk.h[i] = (bf16_t)(of[dt][i] * rl);
        *(ushort4*)&obuf[((size_t)b * N + qrow) * 384 + hl * 48 + 16 * dt + 4 * g] = pk.v;
    }
}

// ---------- host ----------
extern "C" void kernel_launch(void* const* d_in, const int* in_sizes, int n_in,
                              void* d_out, int out_size, void* d_ws, size_t ws_size,
                              hipStream_t stream) {
    const int B = 2, N = 4096, C = 384, N1 = 512, HID = 1536;
    const float* x      = (const float*)d_in[0];
    const float* ln1_w  = (const float*)d_in[1];
    const float* ln1_b  = (const float*)d_in[2];
    const float* q_w    = (const float*)d_in[3];
    const float* sr1_w  = (const float*)d_in[4];
    const float* sr1_b  = (const float*)d_in[5];
    const float* n1_w   = (const float*)d_in[6];
    const float* n1_b   = (const float*)d_in[7];
    const float* sr2_w  = (const float*)d_in[8];
    const float* sr2_b  = (const float*)d_in[9];
    const float* n2_w   = (const float*)d_in[10];
    const float* n2_b   = (const float*)d_in[11];
    const float* kv1_w  = (const float*)d_in[12];
    const float* kv2_w  = (const float*)d_in[13];
    const float* lc1_w  = (const float*)d_in[14];
    const float* lc1_b  = (const float*)d_in[15];
    const float* lc2_w  = (const float*)d_in[16];
    const float* lc2_b  = (const float*)d_in[17];
    const float* proj_w = (const float*)d_in[18];
    const float* proj_b = (const float*)d_in[19];
    const float* ln2_w  = (const float*)d_in[20];
    const float* ln2_b  = (const float*)d_in[21];
    const float* fc1_w  = (const float*)d_in[22];
    const float* fc1_b  = (const float*)d_in[23];
    const float* fc2_w  = (const float*)d_in[24];
    const float* fc2_b  = (const float*)d_in[25];
    float* out = (float*)d_out;

    char* ws = (char*)d_ws;
    // bf16 weight arena
    ushort_t* wq   = (ushort_t*)(ws + 0);
    ushort_t* wsr2 = (ushort_t*)(ws + 294912);
    ushort_t* wkv1 = (ushort_t*)(ws + 589824);
    ushort_t* wkv2 = (ushort_t*)(ws + 884736);
    ushort_t* wproj= (ushort_t*)(ws + 1179648);
    ushort_t* wfc1 = (ushort_t*)(ws + 1474560);
    ushort_t* wfc2 = (ushort_t*)(ws + 2654208);
    ushort_t* wsr1 = (ushort_t*)(ws + 3833856);    // -> 6193152
    // activations
    ushort_t* xa_bf = (ushort_t*)(ws + 6193152);   // [8192][384] bf16; later Obuf
    ushort_t* qbB   = (ushort_t*)(ws + 12484608);  // [8192][384] bf16
    ushort_t* x2_bf = (ushort_t*)(ws + 18776064);  // [8192][384] bf16
    ushort_t* kv2   = (ushort_t*)(ws + 25067520);  // [8192][384] bf16
    ushort_t* vmod2 = (ushort_t*)(ws + 31358976);  // [8192][192] bf16
    ushort_t* kv1   = (ushort_t*)(ws + 34504704);  // [1024][384] bf16
    ushort_t* vmod1 = (ushort_t*)(ws + 35291136);  // [1024][192] bf16
    ushort_t* x1_bf = (ushort_t*)(ws + 35684352);  // [1024][384] bf16
    float*    y2f   = (float*)(ws + 36470784);     // [8192][384] f32; later xres
    float*    y1f   = (float*)(ws + 49053696);     // [1024][384] f32
    ushort_t* A1    = (ushort_t*)(ws + 50626560);  // [1024][3072] bf16; later xm_bf
    ushort_t* hid   = (ushort_t*)(ws + 56918016);  // [8192][1536] bf16 -> 82083840
    ushort_t* vt2   = (ushort_t*)(ws + 82083840);  // [2][192][4096] bf16 -> 85229568
    ushort_t* vt1   = (ushort_t*)(ws + 85229568);  // [2][192][512]  bf16 -> 85622784
    ushort_t* Obuf  = xa_bf;
    float*    xres  = y2f;
    ushort_t* xm_bf = A1;

    // 0. weight conversion (bf16)
    cvt_kernel<<<(147456 + 255) / 256, 256, 0, stream>>>(q_w,   wq,   147456);
    cvt_kernel<<<(147456 + 255) / 256, 256, 0, stream>>>(sr2_w, wsr2, 147456);
    cvt_kernel<<<(147456 + 255) / 256, 256, 0, stream>>>(kv1_w, wkv1, 147456);
    cvt_kernel<<<(147456 + 255) / 256, 256, 0, stream>>>(kv2_w, wkv2, 147456);
    cvt_kernel<<<(147456 + 255) / 256, 256, 0, stream>>>(proj_w, wproj, 147456);
    cvt_kernel<<<(589824 + 255) / 256, 256, 0, stream>>>(fc1_w, wfc1, 589824);
    cvt_kernel<<<(589824 + 255) / 256, 256, 0, stream>>>(fc2_w, wfc2, 589824);
    sr1w_kernel<<<(1179648 + 255) / 256, 256, 0, stream>>>(sr1_w, wsr1, 1179648);

    // 1. xa = LN(x) -> bf16
    ln_kernel<<<B * N, 128, 0, stream>>>(x, ln1_w, ln1_b, nullptr, xa_bf, 0);
    // 2. q = xa @ q_w^T (bf16)
    mfma_gemm<<<dim3(3, 64), 256, 0, stream>>>(xa_bf, wq, nullptr, nullptr,
                                               nullptr, qbB, B * N, C, C, 0);
    // 3. y2 = xa @ sr2_w^T + b (f32)
    mfma_gemm<<<dim3(3, 64), 256, 0, stream>>>(xa_bf, wsr2, sr2_b, nullptr,
                                               y2f, nullptr, B * N, C, C, 0);
    // 4. x2 = gelu(LN(y2)) -> bf16
    ln_kernel<<<B * N, 128, 0, stream>>>(y2f, n2_w, n2_b, nullptr, x2_bf, 1);
    // 5. im2col + sr1 GEMM
    im2col_kernel<<<(1024 * 3072 + 255) / 256, 256, 0, stream>>>(xa_bf, A1);
    mfma_gemm<<<dim3(3, 8), 256, 0, stream>>>(A1, wsr1, sr1_b, nullptr,
                                              y1f, nullptr, 1024, C, 3072, 0);
    // 6. x1 = gelu(LN(y1)) -> bf16
    ln_kernel<<<B * N1, 128, 0, stream>>>(y1f, n1_w, n1_b, nullptr, x1_bf, 1);
    // 7. kv2 = x2 @ kv2_w^T (bf16)
    mfma_gemm<<<dim3(3, 64), 256, 0, stream>>>(x2_bf, wkv2, nullptr, nullptr,
                                               nullptr, kv2, B * N, C, C, 0);
    // 8. kv1 = x1 @ kv1_w^T (bf16)
    mfma_gemm<<<dim3(3, 8), 256, 0, stream>>>(x1_bf, wkv1, nullptr, nullptr,
                                              nullptr, kv1, 1024, C, C, 0);
    // 9/10. vmod = v + dwconv3(v), then transpose -> vt
    {
        int total2 = B * N * 192;
        dwconv_kernel<<<(total2 + 255) / 256, 256, 0, stream>>>(kv2 + 192, lc2_w, lc2_b, vmod2,
                                                                16, 16, 16, N, total2);
        int total1 = B * N1 * 192;
        dwconv_kernel<<<(total1 + 255) / 256, 256, 0, stream>>>(kv1 + 192, lc1_w, lc1_b, vmod1,
                                                                8, 8, 8, N1, total1);
        transpose_kernel<<<dim3(64, 3, 2), 256, 0, stream>>>(vmod2, vt2, 4096);
        transpose_kernel<<<dim3(8, 3, 2), 256, 0, stream>>>(vmod1, vt1, 512);
    }
    // 11. merged attention (8 heads: 4x NK=512, 4x NK=4096)
    attn_mfma2<<<dim3(N / 64, 8, B), 256, 0, stream>>>(qbB, kv1, kv2, vt1, vt2, Obuf);
    // 13. xres = x + O @ proj_w^T + proj_b (f32)
    mfma_gemm<<<dim3(3, 64), 256, 0, stream>>>(Obuf, wproj, proj_b, x,
                                               xres, nullptr, B * N, C, C, 0);
    // 14. xm = LN(xres) -> bf16
    ln_kernel<<<B * N, 128, 0, stream>>>(xres, ln2_w, ln2_b, nullptr, xm_bf, 0);
    // 15. hid = gelu(xm @ fc1^T + b) (bf16)
    mfma_gemm<<<dim3(12, 64), 256, 0, stream>>>(xm_bf, wfc1, fc1_b, nullptr,
                                                nullptr, hid, B * N, HID, C, 1);
    // 16. out = xres + hid @ fc2^T + b (f32 -> d_out)
    mfma_gemm<<<dim3(3, 64), 256, 0, stream>>>(hid, wfc2, fc2_b, xres,
                                               out, nullptr, B * N, C, HID, 0);
}

// Round 8
// 572.727 us; speedup vs baseline: 7.8264x; 1.1763x over previous
//
#include <hip/hip_runtime.h>

typedef unsigned short ushort_t;
typedef unsigned int uint_t;
typedef __bf16 bf16_t;
typedef __bf16 bf16x8 __attribute__((ext_vector_type(8)));
typedef float f32x4 __attribute__((ext_vector_type(4)));

// ---------- helpers ----------
__device__ __forceinline__ float b2f(ushort_t u) {
    union { uint_t i; float f; } v; v.i = ((uint_t)u) << 16; return v.f;
}
__device__ __forceinline__ ushort_t f2b(float f) {
    union { float f; uint_t i; } v; v.f = f;
    uint_t r = v.i + 0x7fffu + ((v.i >> 16) & 1u);
    return (ushort_t)(r >> 16);
}
__device__ __forceinline__ float gelu_exact(float x) {
    return 0.5f * x * (1.0f + erff(x * 0.70710678118654752f));
}

// ---------- all weight conversions in ONE launch ----------
// layout (ushort elements): wq 0, wsr2 147456, wkv1 294912, wkv2 442368,
// wproj 589824, wfc1 737280, wfc2 1327104, wsr1 1916928 (reordered), total 3096576
__global__ void prep_weights(const float* __restrict__ q_w, const float* __restrict__ sr2_w,
                             const float* __restrict__ kv1_w, const float* __restrict__ kv2_w,
                             const float* __restrict__ proj_w, const float* __restrict__ fc1_w,
                             const float* __restrict__ fc2_w, const float* __restrict__ sr1_w,
                             ushort_t* __restrict__ dst) {
    int gid = blockIdx.x * 256 + threadIdx.x;
    int i = gid;
    if (i < 147456) { dst[gid] = f2b(q_w[i]); return; }
    i -= 147456;
    if (i < 147456) { dst[gid] = f2b(sr2_w[i]); return; }
    i -= 147456;
    if (i < 147456) { dst[gid] = f2b(kv1_w[i]); return; }
    i -= 147456;
    if (i < 147456) { dst[gid] = f2b(kv2_w[i]); return; }
    i -= 147456;
    if (i < 147456) { dst[gid] = f2b(proj_w[i]); return; }
    i -= 147456;
    if (i < 589824) { dst[gid] = f2b(fc1_w[i]); return; }
    i -= 589824;
    if (i < 589824) { dst[gid] = f2b(fc2_w[i]); return; }
    i -= 589824;
    if (i < 1179648) {
        int co = i / 3072, r = i % 3072, kk = r / 384, ci = r % 384;
        dst[gid] = f2b(sr1_w[((size_t)co * 384 + ci) * 8 + kk]);
    }
}

// ---------- im2col for sr1 ----------
__global__ void im2col_kernel(const ushort_t* __restrict__ xa, ushort_t* __restrict__ A1) {
    int gid = blockIdx.x * 256 + threadIdx.x;
    if (gid >= 1024 * 3072) return;
    int m = gid / 3072, r = gid % 3072, kk = r / 384, ci = r % 384;
    int b = m >> 9, n1 = m & 511;
    int ho = n1 >> 6, wo = (n1 >> 3) & 7, dz = n1 & 7;
    int n = ((2 * ho + ((kk >> 2) & 1)) << 8) + ((2 * wo + ((kk >> 1) & 1)) << 4) + (2 * dz + (kk & 1));
    A1[gid] = xa[((size_t)b * 4096 + n) * 384 + ci];
}

// ---------- LayerNorm (+ optional GELU); C = 384 ----------
__global__ __launch_bounds__(128) void ln_kernel(const float* __restrict__ in,
                                                 const float* __restrict__ w,
                                                 const float* __restrict__ b,
                                                 float* __restrict__ outf,
                                                 ushort_t* __restrict__ outb, int act) {
    const int C = 384;
    int row = blockIdx.x, tid = threadIdx.x;
    size_t base = (size_t)row * C;
    float x[3], s = 0.f, s2 = 0.f;
#pragma unroll
    for (int i = 0; i < 3; i++) {
        int c = tid + i * 128;
        float v = in[base + c];
        x[i] = v; s += v; s2 += v * v;
    }
    for (int off = 32; off; off >>= 1) { s += __shfl_down(s, off); s2 += __shfl_down(s2, off); }
    __shared__ float sc[4];
    int lane = tid & 63, wid = tid >> 6;
    if (lane == 0) { sc[wid] = s; sc[wid + 2] = s2; }
    __syncthreads();
    float ts = sc[0] + sc[1], ts2 = sc[2] + sc[3];
    float mean = ts / C;
    float var = ts2 / C - mean * mean;
    float rstd = rsqrtf(var + 1e-5f);
#pragma unroll
    for (int i = 0; i < 3; i++) {
        int c = tid + i * 128;
        float v = (x[i] - mean) * rstd * w[c] + b[c];
        if (act) v = gelu_exact(v);
        if (outf) outf[base + c] = v;
        if (outb) outb[base + c] = f2b(v);
    }
}

// ---------- MFMA GEMM: C = act(A @ W^T + bias) (+res). 128x128 tile, BK=32 ----------
__global__ __launch_bounds__(256) void mfma_gemm(const ushort_t* __restrict__ A,
                                                 const ushort_t* __restrict__ W,
                                                 const float* __restrict__ bias,
                                                 const float* __restrict__ res,
                                                 float* __restrict__ outf,
                                                 ushort_t* __restrict__ outb,
                                                 int M, int N, int K, int act) {
    __shared__ bf16_t Asl[128][40];
    __shared__ bf16_t Wsl[128][40];
    int tid = threadIdx.x;
    int wave = tid >> 6, lane = tid & 63, g = lane >> 4, c = lane & 15;
    int wm = wave >> 1, wn = wave & 1;
    int m0 = blockIdx.y * 128, n0 = blockIdx.x * 128;
    int srow = tid >> 1, sseg = tid & 1;

    f32x4 acc[4][4];
#pragma unroll
    for (int i = 0; i < 4; i++)
#pragma unroll
        for (int j = 0; j < 4; j++) acc[i][j] = f32x4{0.f, 0.f, 0.f, 0.f};

    for (int k0 = 0; k0 < K; k0 += 32) {
        const ushort_t* As = A + (size_t)(m0 + srow) * K + k0 + sseg * 16;
        const ushort_t* Ws = W + (size_t)(n0 + srow) * K + k0 + sseg * 16;
        uint4 av0 = *(const uint4*)As, av1 = *(const uint4*)(As + 8);
        uint4 wv0 = *(const uint4*)Ws, wv1 = *(const uint4*)(Ws + 8);
        __syncthreads();
        *(uint4*)&Asl[srow][sseg * 16] = av0;
        *(uint4*)&Asl[srow][sseg * 16 + 8] = av1;
        *(uint4*)&Wsl[srow][sseg * 16] = wv0;
        *(uint4*)&Wsl[srow][sseg * 16 + 8] = wv1;
        __syncthreads();
        bf16x8 af[4], bf[4];
#pragma unroll
        for (int fi = 0; fi < 4; fi++) af[fi] = *(bf16x8*)&Asl[wm * 64 + fi * 16 + c][g * 8];
#pragma unroll
        for (int fj = 0; fj < 4; fj++) bf[fj] = *(bf16x8*)&Wsl[wn * 64 + fj * 16 + c][g * 8];
#pragma unroll
        for (int fi = 0; fi < 4; fi++)
#pragma unroll
            for (int fj = 0; fj < 4; fj++)
                acc[fi][fj] = __builtin_amdgcn_mfma_f32_16x16x32_bf16(af[fi], bf[fj], acc[fi][fj], 0, 0, 0);
    }

#pragma unroll
    for (int fi = 0; fi < 4; fi++) {
#pragma unroll
        for (int fj = 0; fj < 4; fj++) {
            int n = n0 + wn * 64 + fj * 16 + c;
            float bv = bias ? bias[n] : 0.f;
#pragma unroll
            for (int i = 0; i < 4; i++) {
                int m = m0 + wm * 64 + fi * 16 + 4 * g + i;
                float v = acc[fi][fj][i] + bv;
                if (act == 1) v = gelu_exact(v);
                size_t idx = (size_t)m * N + n;
                if (res) v += res[idx];
                if (outf) outf[idx] = v;
                if (outb) outb[idx] = f2b(v);
            }
        }
    }
}

// ---------- depthwise 3x3x3 SAME residual conv on V ----------
__global__ void dwconv_kernel(const ushort_t* __restrict__ vin,
                              const float* __restrict__ wt,
                              const float* __restrict__ bias,
                              ushort_t* __restrict__ vout,
                              int Hs, int Wsz, int Ds, int S, int total) {
    int gid = blockIdx.x * 256 + threadIdx.x;
    if (gid >= total) return;
    int c2 = gid % 192;
    int r = gid / 192;
    int n = r % S;
    int b = r / S;
    int dz = n % Ds, wy = (n / Ds) % Wsz, hx = n / (Wsz * Ds);
    float center = b2f(vin[(size_t)(b * S + n) * 384 + c2]);
    float acc = bias[c2];
    for (int kh = -1; kh <= 1; kh++) {
        int h2 = hx + kh; if (h2 < 0 || h2 >= Hs) continue;
        for (int kw = -1; kw <= 1; kw++) {
            int w2 = wy + kw; if (w2 < 0 || w2 >= Wsz) continue;
            for (int kd = -1; kd <= 1; kd++) {
                int d2 = dz + kd; if (d2 < 0 || d2 >= Ds) continue;
                int nn = (h2 * Wsz + w2) * Ds + d2;
                acc += b2f(vin[(size_t)(b * S + nn) * 384 + c2]) *
                       wt[c2 * 27 + (kh + 1) * 9 + (kw + 1) * 3 + (kd + 1)];
            }
        }
    }
    vout[(size_t)(b * S + n) * 192 + c2] = f2b(center + acc);
}

// ---------- transpose vmod [b][S][192] -> vt [b][192][S] ----------
__global__ __launch_bounds__(256) void transpose_kernel(const ushort_t* __restrict__ src,
                                                        ushort_t* __restrict__ dst, int S) {
    __shared__ ushort_t t_lds[64][65];
    int n0 = blockIdx.x * 64, c0 = blockIdx.y * 64, b = blockIdx.z;
    int tid = threadIdx.x;
#pragma unroll
    for (int i = 0; i < 16; i++) {
        int idx = tid + i * 256;
        int r = idx >> 6, cc = idx & 63;
        t_lds[r][cc] = src[((size_t)b * S + n0 + r) * 192 + c0 + cc];
    }
    __syncthreads();
#pragma unroll
    for (int i = 0; i < 16; i++) {
        int idx = tid + i * 256;
        int r = idx >> 6, cc = idx & 63;
        dst[((size_t)b * 192 + c0 + r) * S + n0 + cc] = t_lds[cc][r];
    }
}

// ---------- MFMA flash attention v3: barrier-free, K/VT direct from global ----------
// hl 0..3: NK=512 (kv1/vt1); hl 4..7: NK=4096 (kv2/vt2). q/o ch = hl*48, kv/vt ch = (hl&3)*48.
// Swapped operands: S^T = mfma(K, Q), O^T = mfma(VT, P); lane owns one q-row (col c).
__global__ __launch_bounds__(256) void attn_mfma3(
    const ushort_t* __restrict__ qbuf,
    const ushort_t* __restrict__ kv1,
    const ushort_t* __restrict__ kv2,
    const ushort_t* __restrict__ vt1,
    const ushort_t* __restrict__ vt2,
    ushort_t* __restrict__ obuf)
{
    __shared__ bf16_t P_lds[64][72];   // wave w owns rows 16w..16w+15 (no cross-wave use)

    const int N = 4096;
    int tid = threadIdx.x;
    int q0 = blockIdx.x * 64, hl = 7 - blockIdx.y, b = blockIdx.z;  // heavy heads first
    int wave = tid >> 6, lane = tid & 63, g = lane >> 4, c = lane & 15;
    const float scale = 0.14433756729740643f;  // 48^-0.5
    int br2 = hl >> 2;
    int NK = br2 ? 4096 : 512;
    const ushort_t* kbuf = br2 ? kv2 : kv1;
    const ushort_t* vtb  = br2 ? vt2 : vt1;
    int hloc = hl & 3;

    union { uint4 u; bf16x8 v; } zz; zz.u = uint4{0u, 0u, 0u, 0u};
    const bf16x8 zero8 = zz.v;

    // ---- Q fragments in registers (constant across k-loop); zero-pad k=48..63 ----
    const ushort_t* qrowp = qbuf + ((size_t)b * N + q0 + 16 * wave + c) * 384 + hl * 48;
    bf16x8 bq0 = *(const bf16x8*)(qrowp + g * 8);
    bf16x8 bq1 = (g < 2) ? *(const bf16x8*)(qrowp + 32 + g * 8) : zero8;

    f32x4 of[3];
#pragma unroll
    for (int dt = 0; dt < 3; dt++) of[dt] = f32x4{0.f, 0.f, 0.f, 0.f};
    float m_run = -1e30f, l_run = 0.f;

    const ushort_t* ksrc0 = kbuf + (size_t)b * NK * 384 + hloc * 48;
    const ushort_t* vsrc0 = vtb + ((size_t)b * 192 + hloc * 48) * NK;
    int nkt = NK >> 6;

    for (int kt = 0; kt < nkt; kt++) {
        // ---- K fragments direct from global (A operand, rows = keys 16t+c) ----
        bf16x8 ak0[4], ak1[4];
#pragma unroll
        for (int t = 0; t < 4; t++) {
            const ushort_t* kr = ksrc0 + (size_t)(kt * 64 + 16 * t + c) * 384;
            ak0[t] = *(const bf16x8*)(kr + g * 8);
            ak1[t] = (g < 2) ? *(const bf16x8*)(kr + 32 + g * 8) : zero8;
        }
        // ---- VT fragments direct from global (A operand, rows = d, k = keys) ----
        bf16x8 av0[3], av1[3];
#pragma unroll
        for (int dt = 0; dt < 3; dt++) {
            const ushort_t* vr = vsrc0 + (size_t)(16 * dt + c) * NK + kt * 64;
            av0[dt] = *(const bf16x8*)(vr + g * 8);
            av1[dt] = *(const bf16x8*)(vr + 32 + g * 8);
        }

        // ---- S^T = K Q^T ----
        f32x4 sf[4];
#pragma unroll
        for (int t = 0; t < 4; t++) sf[t] = f32x4{0.f, 0.f, 0.f, 0.f};
#pragma unroll
        for (int t = 0; t < 4; t++) {
            sf[t] = __builtin_amdgcn_mfma_f32_16x16x32_bf16(ak0[t], bq0, sf[t], 0, 0, 0);
            sf[t] = __builtin_amdgcn_mfma_f32_16x16x32_bf16(ak1[t], bq1, sf[t], 0, 0, 0);
        }

        // ---- online softmax: lane owns q-row c; combine g-groups via xor16/32 ----
        float mx = -1e30f;
#pragma unroll
        for (int t = 0; t < 4; t++)
#pragma unroll
            for (int i = 0; i < 4; i++) mx = fmaxf(mx, sf[t][i]);
        mx *= scale;
        mx = fmaxf(mx, __shfl_xor(mx, 16));
        mx = fmaxf(mx, __shfl_xor(mx, 32));
        float mn = fmaxf(m_run, mx);
        float fct = __expf(m_run - mn);
        m_run = mn;
        float rs = 0.f;
#pragma unroll
        for (int t = 0; t < 4; t++) {
            union { ushort4 v; bf16_t h[4]; } pk;
#pragma unroll
            for (int i = 0; i < 4; i++) {
                float p = __expf(sf[t][i] * scale - mn);
                rs += p;
                pk.h[i] = (bf16_t)p;
            }
            *(ushort4*)&P_lds[16 * wave + c][16 * t + 4 * g] = pk.v;
        }
        rs += __shfl_xor(rs, 16);
        rs += __shfl_xor(rs, 32);
        l_run = l_run * fct + rs;
#pragma unroll
        for (int dt = 0; dt < 3; dt++)
#pragma unroll
            for (int i = 0; i < 4; i++) of[dt][i] *= fct;

        // wave-local P write->read ordering fence
        asm volatile("s_waitcnt lgkmcnt(0)" ::: "memory");

        // ---- O^T += VT P^T ----
        bf16x8 pb0 = *(bf16x8*)&P_lds[16 * wave + c][g * 8];
        bf16x8 pb1 = *(bf16x8*)&P_lds[16 * wave + c][32 + g * 8];
#pragma unroll
        for (int dt = 0; dt < 3; dt++) {
            of[dt] = __builtin_amdgcn_mfma_f32_16x16x32_bf16(av0[dt], pb0, of[dt], 0, 0, 0);
            of[dt] = __builtin_amdgcn_mfma_f32_16x16x32_bf16(av1[dt], pb1, of[dt], 0, 0, 0);
        }
    }

    // ---- epilogue ----
    float rl = 1.f / l_run;
    int qrow = q0 + 16 * wave + c;
#pragma unroll
    for (int dt = 0; dt < 3; dt++) {
        union { ushort4 v; bf16_t h[4]; } pk;
#pragma unroll
        for (int i = 0; i < 4; i++) pk.h[i] = (bf16_t)(of[dt][i] * rl);
        *(ushort4*)&obuf[((size_t)b * N + qrow) * 384 + hl * 48 + 16 * dt + 4 * g] = pk.v;
    }
}

// ---------- host ----------
extern "C" void kernel_launch(void* const* d_in, const int* in_sizes, int n_in,
                              void* d_out, int out_size, void* d_ws, size_t ws_size,
                              hipStream_t stream) {
    const int B = 2, N = 4096, C = 384, N1 = 512, HID = 1536;
    const float* x      = (const float*)d_in[0];
    const float* ln1_w  = (const float*)d_in[1];
    const float* ln1_b  = (const float*)d_in[2];
    const float* q_w    = (const float*)d_in[3];
    const float* sr1_w  = (const float*)d_in[4];
    const float* sr1_b  = (const float*)d_in[5];
    const float* n1_w   = (const float*)d_in[6];
    const float* n1_b   = (const float*)d_in[7];
    const float* sr2_w  = (const float*)d_in[8];
    const float* sr2_b  = (const float*)d_in[9];
    const float* n2_w   = (const float*)d_in[10];
    const float* n2_b   = (const float*)d_in[11];
    const float* kv1_w  = (const float*)d_in[12];
    const float* kv2_w  = (const float*)d_in[13];
    const float* lc1_w  = (const float*)d_in[14];
    const float* lc1_b  = (const float*)d_in[15];
    const float* lc2_w  = (const float*)d_in[16];
    const float* lc2_b  = (const float*)d_in[17];
    const float* proj_w = (const float*)d_in[18];
    const float* proj_b = (const float*)d_in[19];
    const float* ln2_w  = (const float*)d_in[20];
    const float* ln2_b  = (const float*)d_in[21];
    const float* fc1_w  = (const float*)d_in[22];
    const float* fc1_b  = (const float*)d_in[23];
    const float* fc2_w  = (const float*)d_in[24];
    const float* fc2_b  = (const float*)d_in[25];
    float* out = (float*)d_out;

    char* ws = (char*)d_ws;
    // bf16 weight arena (contiguous; filled by prep_weights)
    ushort_t* wbase = (ushort_t*)ws;
    ushort_t* wq   = wbase;                 // el 0
    ushort_t* wsr2 = wbase + 147456;
    ushort_t* wkv1 = wbase + 294912;
    ushort_t* wkv2 = wbase + 442368;
    ushort_t* wproj= wbase + 589824;
    ushort_t* wfc1 = wbase + 737280;
    ushort_t* wfc2 = wbase + 1327104;
    ushort_t* wsr1 = wbase + 1916928;       // -> el 3096576 (byte 6193152)
    // activations
    ushort_t* xa_bf = (ushort_t*)(ws + 6193152);   // [8192][384] bf16; later Obuf
    ushort_t* qbB   = (ushort_t*)(ws + 12484608);  // [8192][384] bf16
    ushort_t* x2_bf = (ushort_t*)(ws + 18776064);  // [8192][384] bf16
    ushort_t* kv2   = (ushort_t*)(ws + 25067520);  // [8192][384] bf16
    ushort_t* vmod2 = (ushort_t*)(ws + 31358976);  // [8192][192] bf16
    ushort_t* kv1   = (ushort_t*)(ws + 34504704);  // [1024][384] bf16
    ushort_t* vmod1 = (ushort_t*)(ws + 35291136);  // [1024][192] bf16
    ushort_t* x1_bf = (ushort_t*)(ws + 35684352);  // [1024][384] bf16
    float*    y2f   = (float*)(ws + 36470784);     // [8192][384] f32; later xres
    float*    y1f   = (float*)(ws + 49053696);     // [1024][384] f32
    ushort_t* A1    = (ushort_t*)(ws + 50626560);  // [1024][3072] bf16; later xm_bf
    ushort_t* hid   = (ushort_t*)(ws + 56918016);  // [8192][1536] bf16 -> 82083840
    ushort_t* vt2   = (ushort_t*)(ws + 82083840);  // [2][192][4096] bf16 -> 85229568
    ushort_t* vt1   = (ushort_t*)(ws + 85229568);  // [2][192][512]  bf16 -> 85622784
    ushort_t* Obuf  = xa_bf;
    float*    xres  = y2f;
    ushort_t* xm_bf = A1;

    // 0. all weight conversions, one launch (3096576 elements)
    prep_weights<<<(3096576 + 255) / 256, 256, 0, stream>>>(q_w, sr2_w, kv1_w, kv2_w,
                                                            proj_w, fc1_w, fc2_w, sr1_w, wbase);

    // 1. xa = LN(x) -> bf16
    ln_kernel<<<B * N, 128, 0, stream>>>(x, ln1_w, ln1_b, nullptr, xa_bf, 0);
    // 2. q = xa @ q_w^T (bf16)
    mfma_gemm<<<dim3(3, 64), 256, 0, stream>>>(xa_bf, wq, nullptr, nullptr,
                                               nullptr, qbB, B * N, C, C, 0);
    // 3. y2 = xa @ sr2_w^T + b (f32)
    mfma_gemm<<<dim3(3, 64), 256, 0, stream>>>(xa_bf, wsr2, sr2_b, nullptr,
                                               y2f, nullptr, B * N, C, C, 0);
    // 4. x2 = gelu(LN(y2)) -> bf16
    ln_kernel<<<B * N, 128, 0, stream>>>(y2f, n2_w, n2_b, nullptr, x2_bf, 1);
    // 5. im2col + sr1 GEMM
    im2col_kernel<<<(1024 * 3072 + 255) / 256, 256, 0, stream>>>(xa_bf, A1);
    mfma_gemm<<<dim3(3, 8), 256, 0, stream>>>(A1, wsr1, sr1_b, nullptr,
                                              y1f, nullptr, 1024, C, 3072, 0);
    // 6. x1 = gelu(LN(y1)) -> bf16
    ln_kernel<<<B * N1, 128, 0, stream>>>(y1f, n1_w, n1_b, nullptr, x1_bf, 1);
    // 7. kv2 = x2 @ kv2_w^T (bf16)
    mfma_gemm<<<dim3(3, 64), 256, 0, stream>>>(x2_bf, wkv2, nullptr, nullptr,
                                               nullptr, kv2, B * N, C, C, 0);
    // 8. kv1 = x1 @ kv1_w^T (bf16)
    mfma_gemm<<<dim3(3, 8), 256, 0, stream>>>(x1_bf, wkv1, nullptr, nullptr,
                                              nullptr, kv1, 1024, C, C, 0);
    // 9/10. vmod = v + dwconv3(v), then transpose -> vt
    {
        int total2 = B * N * 192;
        dwconv_kernel<<<(total2 + 255) / 256, 256, 0, stream>>>(kv2 + 192, lc2_w, lc2_b, vmod2,
                                                                16, 16, 16, N, total2);
        int total1 = B * N1 * 192;
        dwconv_kernel<<<(total1 + 255) / 256, 256, 0, stream>>>(kv1 + 192, lc1_w, lc1_b, vmod1,
                                                                8, 8, 8, N1, total1);
        transpose_kernel<<<dim3(64, 3, 2), 256, 0, stream>>>(vmod2, vt2, 4096);
        transpose_kernel<<<dim3(8, 3, 2), 256, 0, stream>>>(vmod1, vt1, 512);
    }
    // 11. merged attention (heavy heads first via hl = 7 - blockIdx.y)
    attn_mfma3<<<dim3(N / 64, 8, B), 256, 0, stream>>>(qbB, kv1, kv2, vt1, vt2, Obuf);
    // 13. xres = x + O @ proj_w^T + proj_b (f32)
    mfma_gemm<<<dim3(3, 64), 256, 0, stream>>>(Obuf, wproj, proj_b, x,
                                               xres, nullptr, B * N, C, C, 0);
    // 14. xm = LN(xres) -> bf16
    ln_kernel<<<B * N, 128, 0, stream>>>(xres, ln2_w, ln2_b, nullptr, xm_bf, 0);
    // 15. hid = gelu(xm @ fc1^T + b) (bf16)
    mfma_gemm<<<dim3(12, 64), 256, 0, stream>>>(xm_bf, wfc1, fc1_b, nullptr,
                                                nullptr, hid, B * N, HID, C, 1);
    // 16. out = xres + hid @ fc2^T + b (f32 -> d_out)
    mfma_gemm<<<dim3(3, 64), 256, 0, stream>>>(hid, wfc2, fc2_b, xres,
                                               out, nullptr, B * N, C, HID, 0);
}

// Round 9
// 351.197 us; speedup vs baseline: 12.7632x; 1.6308x over previous
//
#include <hip/hip_runtime.h>

typedef unsigned short ushort_t;
typedef unsigned int uint_t;
typedef __bf16 bf16_t;
typedef __bf16 bf16x8 __attribute__((ext_vector_type(8)));
typedef float f32x4 __attribute__((ext_vector_type(4)));

// ---------- helpers ----------
__device__ __forceinline__ float b2f(ushort_t u) {
    union { uint_t i; float f; } v; v.i = ((uint_t)u) << 16; return v.f;
}
__device__ __forceinline__ ushort_t f2b(float f) {
    union { float f; uint_t i; } v; v.f = f;
    uint_t r = v.i + 0x7fffu + ((v.i >> 16) & 1u);
    return (ushort_t)(r >> 16);
}
__device__ __forceinline__ float gelu_exact(float x) {
    return 0.5f * x * (1.0f + erff(x * 0.70710678118654752f));
}

// ---------- all weight conversions in ONE launch ----------
__global__ void prep_weights(const float* __restrict__ q_w, const float* __restrict__ sr2_w,
                             const float* __restrict__ kv1_w, const float* __restrict__ kv2_w,
                             const float* __restrict__ proj_w, const float* __restrict__ fc1_w,
                             const float* __restrict__ fc2_w, const float* __restrict__ sr1_w,
                             ushort_t* __restrict__ dst) {
    int gid = blockIdx.x * 256 + threadIdx.x;
    int i = gid;
    if (i < 147456) { dst[gid] = f2b(q_w[i]); return; }
    i -= 147456;
    if (i < 147456) { dst[gid] = f2b(sr2_w[i]); return; }
    i -= 147456;
    if (i < 147456) { dst[gid] = f2b(kv1_w[i]); return; }
    i -= 147456;
    if (i < 147456) { dst[gid] = f2b(kv2_w[i]); return; }
    i -= 147456;
    if (i < 147456) { dst[gid] = f2b(proj_w[i]); return; }
    i -= 147456;
    if (i < 589824) { dst[gid] = f2b(fc1_w[i]); return; }
    i -= 589824;
    if (i < 589824) { dst[gid] = f2b(fc2_w[i]); return; }
    i -= 589824;
    if (i < 1179648) {
        int co = i / 3072, r = i % 3072, kk = r / 384, ci = r % 384;
        dst[gid] = f2b(sr1_w[((size_t)co * 384 + ci) * 8 + kk]);
    }
}

// ---------- im2col for sr1 ----------
__global__ void im2col_kernel(const ushort_t* __restrict__ xa, ushort_t* __restrict__ A1) {
    int gid = blockIdx.x * 256 + threadIdx.x;
    if (gid >= 1024 * 3072) return;
    int m = gid / 3072, r = gid % 3072, kk = r / 384, ci = r % 384;
    int b = m >> 9, n1 = m & 511;
    int ho = n1 >> 6, wo = (n1 >> 3) & 7, dz = n1 & 7;
    int n = ((2 * ho + ((kk >> 2) & 1)) << 8) + ((2 * wo + ((kk >> 1) & 1)) << 4) + (2 * dz + (kk & 1));
    A1[gid] = xa[((size_t)b * 4096 + n) * 384 + ci];
}

// ---------- LayerNorm (+ optional GELU); C = 384 ----------
__global__ __launch_bounds__(128) void ln_kernel(const float* __restrict__ in,
                                                 const float* __restrict__ w,
                                                 const float* __restrict__ b,
                                                 float* __restrict__ outf,
                                                 ushort_t* __restrict__ outb, int act) {
    const int C = 384;
    int row = blockIdx.x, tid = threadIdx.x;
    size_t base = (size_t)row * C;
    float x[3], s = 0.f, s2 = 0.f;
#pragma unroll
    for (int i = 0; i < 3; i++) {
        int c = tid + i * 128;
        float v = in[base + c];
        x[i] = v; s += v; s2 += v * v;
    }
    for (int off = 32; off; off >>= 1) { s += __shfl_down(s, off); s2 += __shfl_down(s2, off); }
    __shared__ float sc[4];
    int lane = tid & 63, wid = tid >> 6;
    if (lane == 0) { sc[wid] = s; sc[wid + 2] = s2; }
    __syncthreads();
    float ts = sc[0] + sc[1], ts2 = sc[2] + sc[3];
    float mean = ts / C;
    float var = ts2 / C - mean * mean;
    float rstd = rsqrtf(var + 1e-5f);
#pragma unroll
    for (int i = 0; i < 3; i++) {
        int c = tid + i * 128;
        float v = (x[i] - mean) * rstd * w[c] + b[c];
        if (act) v = gelu_exact(v);
        if (outf) outf[base + c] = v;
        if (outb) outb[base + c] = f2b(v);
    }
}

// ---------- MFMA GEMM 128x128, BK=32 (used for fc1) ----------
__global__ __launch_bounds__(256) void mfma_gemm(const ushort_t* __restrict__ A,
                                                 const ushort_t* __restrict__ W,
                                                 const float* __restrict__ bias,
                                                 const float* __restrict__ res,
                                                 float* __restrict__ outf,
                                                 ushort_t* __restrict__ outb,
                                                 int M, int N, int K, int act) {
    __shared__ bf16_t Asl[128][40];
    __shared__ bf16_t Wsl[128][40];
    int tid = threadIdx.x;
    int wave = tid >> 6, lane = tid & 63, g = lane >> 4, c = lane & 15;
    int wm = wave >> 1, wn = wave & 1;
    int m0 = blockIdx.y * 128, n0 = blockIdx.x * 128;
    int srow = tid >> 1, sseg = tid & 1;

    f32x4 acc[4][4];
#pragma unroll
    for (int i = 0; i < 4; i++)
#pragma unroll
        for (int j = 0; j < 4; j++) acc[i][j] = f32x4{0.f, 0.f, 0.f, 0.f};

    for (int k0 = 0; k0 < K; k0 += 32) {
        const ushort_t* As = A + (size_t)(m0 + srow) * K + k0 + sseg * 16;
        const ushort_t* Ws = W + (size_t)(n0 + srow) * K + k0 + sseg * 16;
        uint4 av0 = *(const uint4*)As, av1 = *(const uint4*)(As + 8);
        uint4 wv0 = *(const uint4*)Ws, wv1 = *(const uint4*)(Ws + 8);
        __syncthreads();
        *(uint4*)&Asl[srow][sseg * 16] = av0;
        *(uint4*)&Asl[srow][sseg * 16 + 8] = av1;
        *(uint4*)&Wsl[srow][sseg * 16] = wv0;
        *(uint4*)&Wsl[srow][sseg * 16 + 8] = wv1;
        __syncthreads();
        bf16x8 af[4], bf[4];
#pragma unroll
        for (int fi = 0; fi < 4; fi++) af[fi] = *(bf16x8*)&Asl[wm * 64 + fi * 16 + c][g * 8];
#pragma unroll
        for (int fj = 0; fj < 4; fj++) bf[fj] = *(bf16x8*)&Wsl[wn * 64 + fj * 16 + c][g * 8];
#pragma unroll
        for (int fi = 0; fi < 4; fi++)
#pragma unroll
            for (int fj = 0; fj < 4; fj++)
                acc[fi][fj] = __builtin_amdgcn_mfma_f32_16x16x32_bf16(af[fi], bf[fj], acc[fi][fj], 0, 0, 0);
    }

#pragma unroll
    for (int fi = 0; fi < 4; fi++) {
#pragma unroll
        for (int fj = 0; fj < 4; fj++) {
            int n = n0 + wn * 64 + fj * 16 + c;
            float bv = bias ? bias[n] : 0.f;
#pragma unroll
            for (int i = 0; i < 4; i++) {
                int m = m0 + wm * 64 + fi * 16 + 4 * g + i;
                float v = acc[fi][fj][i] + bv;
                if (act == 1) v = gelu_exact(v);
                size_t idx = (size_t)m * N + n;
                if (res) v += res[idx];
                if (outf) outf[idx] = v;
                if (outb) outb[idx] = f2b(v);
            }
        }
    }
}

// ---------- MFMA GEMM 64x64, BK=64 (better grid for N=384 layers) ----------
__global__ __launch_bounds__(256) void gemm64(const ushort_t* __restrict__ A,
                                              const ushort_t* __restrict__ W,
                                              const float* __restrict__ bias,
                                              const float* __restrict__ res,
                                              float* __restrict__ outf,
                                              ushort_t* __restrict__ outb,
                                              int M, int N, int K, int act) {
    __shared__ bf16_t Asl[64][72];
    __shared__ bf16_t Wsl[64][72];
    int tid = threadIdx.x;
    int wave = tid >> 6, lane = tid & 63, g = lane >> 4, c = lane & 15;
    int wm = wave >> 1, wn = wave & 1;
    int m0 = blockIdx.y * 64, n0 = blockIdx.x * 64;
    int srow = tid >> 2, sseg = tid & 3;

    f32x4 acc[2][2];
#pragma unroll
    for (int i = 0; i < 2; i++)
#pragma unroll
        for (int j = 0; j < 2; j++) acc[i][j] = f32x4{0.f, 0.f, 0.f, 0.f};

    for (int k0 = 0; k0 < K; k0 += 64) {
        const ushort_t* As = A + (size_t)(m0 + srow) * K + k0 + sseg * 16;
        const ushort_t* Ws = W + (size_t)(n0 + srow) * K + k0 + sseg * 16;
        uint4 av0 = *(const uint4*)As, av1 = *(const uint4*)(As + 8);
        uint4 wv0 = *(const uint4*)Ws, wv1 = *(const uint4*)(Ws + 8);
        __syncthreads();
        *(uint4*)&Asl[srow][sseg * 16] = av0;
        *(uint4*)&Asl[srow][sseg * 16 + 8] = av1;
        *(uint4*)&Wsl[srow][sseg * 16] = wv0;
        *(uint4*)&Wsl[srow][sseg * 16 + 8] = wv1;
        __syncthreads();
#pragma unroll
        for (int kk = 0; kk < 2; kk++) {
            bf16x8 af[2], bf[2];
#pragma unroll
            for (int fi = 0; fi < 2; fi++) af[fi] = *(bf16x8*)&Asl[wm * 32 + fi * 16 + c][kk * 32 + g * 8];
#pragma unroll
            for (int fj = 0; fj < 2; fj++) bf[fj] = *(bf16x8*)&Wsl[wn * 32 + fj * 16 + c][kk * 32 + g * 8];
#pragma unroll
            for (int fi = 0; fi < 2; fi++)
#pragma unroll
                for (int fj = 0; fj < 2; fj++)
                    acc[fi][fj] = __builtin_amdgcn_mfma_f32_16x16x32_bf16(af[fi], bf[fj], acc[fi][fj], 0, 0, 0);
        }
    }

#pragma unroll
    for (int fi = 0; fi < 2; fi++) {
#pragma unroll
        for (int fj = 0; fj < 2; fj++) {
            int n = n0 + wn * 32 + fj * 16 + c;
            float bv = bias ? bias[n] : 0.f;
#pragma unroll
            for (int i = 0; i < 4; i++) {
                int m = m0 + wm * 32 + fi * 16 + 4 * g + i;
                float v = acc[fi][fj][i] + bv;
                if (act == 1) v = gelu_exact(v);
                size_t idx = (size_t)m * N + n;
                if (res) v += res[idx];
                if (outf) outf[idx] = v;
                if (outb) outb[idx] = f2b(v);
            }
        }
    }
}

// ---------- depthwise 3x3x3 SAME residual conv on V ----------
__global__ void dwconv_kernel(const ushort_t* __restrict__ vin,
                              const float* __restrict__ wt,
                              const float* __restrict__ bias,
                              ushort_t* __restrict__ vout,
                              int Hs, int Wsz, int Ds, int S, int total) {
    int gid = blockIdx.x * 256 + threadIdx.x;
    if (gid >= total) return;
    int c2 = gid % 192;
    int r = gid / 192;
    int n = r % S;
    int b = r / S;
    int dz = n % Ds, wy = (n / Ds) % Wsz, hx = n / (Wsz * Ds);
    float center = b2f(vin[(size_t)(b * S + n) * 384 + c2]);
    float acc = bias[c2];
    for (int kh = -1; kh <= 1; kh++) {
        int h2 = hx + kh; if (h2 < 0 || h2 >= Hs) continue;
        for (int kw = -1; kw <= 1; kw++) {
            int w2 = wy + kw; if (w2 < 0 || w2 >= Wsz) continue;
            for (int kd = -1; kd <= 1; kd++) {
                int d2 = dz + kd; if (d2 < 0 || d2 >= Ds) continue;
                int nn = (h2 * Wsz + w2) * Ds + d2;
                acc += b2f(vin[(size_t)(b * S + nn) * 384 + c2]) *
                       wt[c2 * 27 + (kh + 1) * 9 + (kw + 1) * 3 + (kd + 1)];
            }
        }
    }
    vout[(size_t)(b * S + n) * 192 + c2] = f2b(center + acc);
}

// ---------- transpose vmod [b][S][192] -> vt [b][192][S] ----------
__global__ __launch_bounds__(256) void transpose_kernel(const ushort_t* __restrict__ src,
                                                        ushort_t* __restrict__ dst, int S) {
    __shared__ ushort_t t_lds[64][65];
    int n0 = blockIdx.x * 64, c0 = blockIdx.y * 64, b = blockIdx.z;
    int tid = threadIdx.x;
#pragma unroll
    for (int i = 0; i < 16; i++) {
        int idx = tid + i * 256;
        int r = idx >> 6, cc = idx & 63;
        t_lds[r][cc] = src[((size_t)b * S + n0 + r) * 192 + c0 + cc];
    }
    __syncthreads();
#pragma unroll
    for (int i = 0; i < 16; i++) {
        int idx = tid + i * 256;
        int r = idx >> 6, cc = idx & 63;
        dst[((size_t)b * 192 + c0 + r) * S + n0 + cc] = t_lds[cc][r];
    }
}

// ---------- MFMA flash attention v4: 32 q/block, wave-split-K, cross-wave combine ----------
// grid (N/32, 8, 2). hl 0..3: NK=512; hl 4..7: NK=4096. Wave w handles keys [w*NK/4, ...).
__global__ __launch_bounds__(256, 4) void attn_mfma4(
    const ushort_t* __restrict__ qbuf,
    const ushort_t* __restrict__ kv1,
    const ushort_t* __restrict__ kv2,
    const ushort_t* __restrict__ vt1,
    const ushort_t* __restrict__ vt2,
    ushort_t* __restrict__ obuf)
{
    __shared__ __align__(16) char lds_raw[18432];
    bf16_t (*P)[32][72] = (bf16_t (*)[32][72])lds_raw;   // per-wave P tile [q 32][key 64+pad]
    float (*CF)[64][15] = (float (*)[64][15])lds_raw;    // combine buffer (reused after k-loop)

    const int N = 4096;
    int tid = threadIdx.x;
    int q0 = blockIdx.x * 32, hl = 7 - blockIdx.y, b = blockIdx.z;
    int wave = tid >> 6, lane = tid & 63, g = lane >> 4, c = lane & 15;
    const float scale = 0.14433756729740643f;  // 48^-0.5
    int br2 = hl >> 2;
    int NK = br2 ? 4096 : 512;
    const ushort_t* kbuf = br2 ? kv2 : kv1;
    const ushort_t* vtb  = br2 ? vt2 : vt1;
    int hloc = hl & 3;
    int NKc = NK >> 2;
    int kb0 = wave * NKc;
    int nkt = NKc >> 6;

    union { uint4 u; bf16x8 v; } zz; zz.u = uint4{0u, 0u, 0u, 0u};
    const bf16x8 zero8 = zz.v;

    // ---- Q B-fragments in registers (2 q-groups of 16), zero-pad k=48..63 ----
    bf16x8 bq0[2], bq1[2];
#pragma unroll
    for (int qg = 0; qg < 2; qg++) {
        const ushort_t* qrowp = qbuf + ((size_t)b * N + q0 + qg * 16 + c) * 384 + hl * 48;
        bq0[qg] = *(const bf16x8*)(qrowp + g * 8);
        bq1[qg] = (g < 2) ? *(const bf16x8*)(qrowp + 32 + g * 8) : zero8;
    }

    f32x4 of[3][2];
#pragma unroll
    for (int dt = 0; dt < 3; dt++)
#pragma unroll
        for (int qg = 0; qg < 2; qg++) of[dt][qg] = f32x4{0.f, 0.f, 0.f, 0.f};
    float m_run[2] = {-1e30f, -1e30f}, l_run[2] = {0.f, 0.f};

    // lane base pointers (advance by constants)
    const ushort_t* kp = kbuf + ((size_t)b * NK + kb0 + c) * 384 + hloc * 48;
    const ushort_t* vp = vtb + ((size_t)b * 192 + hloc * 48 + c) * NK + kb0;

    for (int kt = 0; kt < nkt; kt++) {
        // ---- S^T = K Q^T ----
        f32x4 sf[4][2];
#pragma unroll
        for (int t = 0; t < 4; t++)
#pragma unroll
            for (int qg = 0; qg < 2; qg++) sf[t][qg] = f32x4{0.f, 0.f, 0.f, 0.f};
#pragma unroll
        for (int t = 0; t < 4; t++) {
            const ushort_t* kr = kp + (size_t)(kt * 64 + 16 * t) * 384;
            bf16x8 ak0 = *(const bf16x8*)(kr + g * 8);
            bf16x8 ak1 = (g < 2) ? *(const bf16x8*)(kr + 32 + g * 8) : zero8;
#pragma unroll
            for (int qg = 0; qg < 2; qg++) {
                sf[t][qg] = __builtin_amdgcn_mfma_f32_16x16x32_bf16(ak0, bq0[qg], sf[t][qg], 0, 0, 0);
                sf[t][qg] = __builtin_amdgcn_mfma_f32_16x16x32_bf16(ak1, bq1[qg], sf[t][qg], 0, 0, 0);
            }
        }

        // ---- online softmax per q-group (lane owns q-row qg*16+c) ----
#pragma unroll
        for (int qg = 0; qg < 2; qg++) {
            float mx = -1e30f;
#pragma unroll
            for (int t = 0; t < 4; t++)
#pragma unroll
                for (int i = 0; i < 4; i++) mx = fmaxf(mx, sf[t][qg][i]);
            mx *= scale;
            mx = fmaxf(mx, __shfl_xor(mx, 16));
            mx = fmaxf(mx, __shfl_xor(mx, 32));
            float mn = fmaxf(m_run[qg], mx);
            float fct = __expf(m_run[qg] - mn);
            m_run[qg] = mn;
            float rs = 0.f;
#pragma unroll
            for (int t = 0; t < 4; t++) {
                union { ushort4 v; bf16_t h[4]; } pk;
#pragma unroll
                for (int i = 0; i < 4; i++) {
                    float p = __expf(sf[t][qg][i] * scale - mn);
                    rs += p;
                    pk.h[i] = (bf16_t)p;
                }
                *(ushort4*)&P[wave][qg * 16 + c][16 * t + 4 * g] = pk.v;
            }
            rs += __shfl_xor(rs, 16);
            rs += __shfl_xor(rs, 32);
            l_run[qg] = l_run[qg] * fct + rs;
#pragma unroll
            for (int dt = 0; dt < 3; dt++)
#pragma unroll
                for (int i = 0; i < 4; i++) of[dt][qg][i] *= fct;
        }

        // wave-local P write->read ordering fence
        asm volatile("s_waitcnt lgkmcnt(0)" ::: "memory");

        // ---- O^T += VT P^T ----
        bf16x8 pb0[2], pb1[2];
#pragma unroll
        for (int qg = 0; qg < 2; qg++) {
            pb0[qg] = *(bf16x8*)&P[wave][qg * 16 + c][g * 8];
            pb1[qg] = *(bf16x8*)&P[wave][qg * 16 + c][32 + g * 8];
        }
#pragma unroll
        for (int dt = 0; dt < 3; dt++) {
            const ushort_t* vr = vp + (size_t)(16 * dt) * NK + kt * 64;
            bf16x8 av0 = *(const bf16x8*)(vr + g * 8);
            bf16x8 av1 = *(const bf16x8*)(vr + 32 + g * 8);
#pragma unroll
            for (int qg = 0; qg < 2; qg++) {
                of[dt][qg] = __builtin_amdgcn_mfma_f32_16x16x32_bf16(av0, pb0[qg], of[dt][qg], 0, 0, 0);
                of[dt][qg] = __builtin_amdgcn_mfma_f32_16x16x32_bf16(av1, pb1[qg], of[dt][qg], 0, 0, 0);
            }
        }
    }

    // ---- cross-wave combine (waves hold disjoint key chunks of the SAME q-rows) ----
#pragma unroll
    for (int qg = 0; qg < 2; qg++) {
        __syncthreads();   // previous use of lds_raw (P / prior round) complete
        float* cfp = &CF[wave][lane][0];
#pragma unroll
        for (int dt = 0; dt < 3; dt++)
#pragma unroll
            for (int i = 0; i < 4; i++) cfp[dt * 4 + i] = of[dt][qg][i];
        cfp[12] = m_run[qg];
        cfp[13] = l_run[qg];
        __syncthreads();
        if (wave == 0) {
            float m4 = CF[0][lane][12];
#pragma unroll
            for (int w = 1; w < 4; w++) m4 = fmaxf(m4, CF[w][lane][12]);
            float lsum = 0.f;
            float oc[12];
#pragma unroll
            for (int j = 0; j < 12; j++) oc[j] = 0.f;
#pragma unroll
            for (int w = 0; w < 4; w++) {
                float e = __expf(CF[w][lane][12] - m4);
                lsum += e * CF[w][lane][13];
#pragma unroll
                for (int j = 0; j < 12; j++) oc[j] += e * CF[w][lane][j];
            }
            float rl = 1.f / lsum;
            int qrow = q0 + qg * 16 + c;
#pragma unroll
            for (int dt = 0; dt < 3; dt++) {
                union { ushort4 v; bf16_t h[4]; } pk;
#pragma unroll
                for (int i = 0; i < 4; i++) pk.h[i] = (bf16_t)(oc[dt * 4 + i] * rl);
                *(ushort4*)&obuf[((size_t)b * N + qrow) * 384 + hl * 48 + 16 * dt + 4 * g] = pk.v;
            }
        }
    }
}

// ---------- host ----------
extern "C" void kernel_launch(void* const* d_in, const int* in_sizes, int n_in,
                              void* d_out, int out_size, void* d_ws, size_t ws_size,
                              hipStream_t stream) {
    const int B = 2, N = 4096, C = 384, N1 = 512, HID = 1536;
    const float* x      = (const float*)d_in[0];
    const float* ln1_w  = (const float*)d_in[1];
    const float* ln1_b  = (const float*)d_in[2];
    const float* q_w    = (const float*)d_in[3];
    const float* sr1_w  = (const float*)d_in[4];
    const float* sr1_b  = (const float*)d_in[5];
    const float* n1_w   = (const float*)d_in[6];
    const float* n1_b   = (const float*)d_in[7];
    const float* sr2_w  = (const float*)d_in[8];
    const float* sr2_b  = (const float*)d_in[9];
    const float* n2_w   = (const float*)d_in[10];
    const float* n2_b   = (const float*)d_in[11];
    const float* kv1_w  = (const float*)d_in[12];
    const float* kv2_w  = (const float*)d_in[13];
    const float* lc1_w  = (const float*)d_in[14];
    const float* lc1_b  = (const float*)d_in[15];
    const float* lc2_w  = (const float*)d_in[16];
    const float* lc2_b  = (const float*)d_in[17];
    const float* proj_w = (const float*)d_in[18];
    const float* proj_b = (const float*)d_in[19];
    const float* ln2_w  = (const float*)d_in[20];
    const float* ln2_b  = (const float*)d_in[21];
    const float* fc1_w  = (const float*)d_in[22];
    const float* fc1_b  = (const float*)d_in[23];
    const float* fc2_w  = (const float*)d_in[24];
    const float* fc2_b  = (const float*)d_in[25];
    float* out = (float*)d_out;

    char* ws = (char*)d_ws;
    ushort_t* wbase = (ushort_t*)ws;
    ushort_t* wq   = wbase;
    ushort_t* wsr2 = wbase + 147456;
    ushort_t* wkv1 = wbase + 294912;
    ushort_t* wkv2 = wbase + 442368;
    ushort_t* wproj= wbase + 589824;
    ushort_t* wfc1 = wbase + 737280;
    ushort_t* wfc2 = wbase + 1327104;
    ushort_t* wsr1 = wbase + 1916928;
    ushort_t* xa_bf = (ushort_t*)(ws + 6193152);
    ushort_t* qbB   = (ushort_t*)(ws + 12484608);
    ushort_t* x2_bf = (ushort_t*)(ws + 18776064);
    ushort_t* kv2   = (ushort_t*)(ws + 25067520);
    ushort_t* vmod2 = (ushort_t*)(ws + 31358976);
    ushort_t* kv1   = (ushort_t*)(ws + 34504704);
    ushort_t* vmod1 = (ushort_t*)(ws + 35291136);
    ushort_t* x1_bf = (ushort_t*)(ws + 35684352);
    float*    y2f   = (float*)(ws + 36470784);
    float*    y1f   = (float*)(ws + 49053696);
    ushort_t* A1    = (ushort_t*)(ws + 50626560);
    ushort_t* hid   = (ushort_t*)(ws + 56918016);
    ushort_t* vt2   = (ushort_t*)(ws + 82083840);
    ushort_t* vt1   = (ushort_t*)(ws + 85229568);
    ushort_t* Obuf  = xa_bf;
    float*    xres  = y2f;
    ushort_t* xm_bf = A1;

    // 0. weights
    prep_weights<<<(3096576 + 255) / 256, 256, 0, stream>>>(q_w, sr2_w, kv1_w, kv2_w,
                                                            proj_w, fc1_w, fc2_w, sr1_w, wbase);
    // 1. xa = LN(x) -> bf16
    ln_kernel<<<B * N, 128, 0, stream>>>(x, ln1_w, ln1_b, nullptr, xa_bf, 0);
    // 2. q = xa @ q_w^T (bf16)
    gemm64<<<dim3(6, 128), 256, 0, stream>>>(xa_bf, wq, nullptr, nullptr,
                                             nullptr, qbB, B * N, C, C, 0);
    // 3. y2 = xa @ sr2_w^T + b (f32)
    gemm64<<<dim3(6, 128), 256, 0, stream>>>(xa_bf, wsr2, sr2_b, nullptr,
                                             y2f, nullptr, B * N, C, C, 0);
    // 4. x2 = gelu(LN(y2)) -> bf16
    ln_kernel<<<B * N, 128, 0, stream>>>(y2f, n2_w, n2_b, nullptr, x2_bf, 1);
    // 5. im2col + sr1 GEMM
    im2col_kernel<<<(1024 * 3072 + 255) / 256, 256, 0, stream>>>(xa_bf, A1);
    gemm64<<<dim3(6, 16), 256, 0, stream>>>(A1, wsr1, sr1_b, nullptr,
                                            y1f, nullptr, 1024, C, 3072, 0);
    // 6. x1 = gelu(LN(y1)) -> bf16
    ln_kernel<<<B * N1, 128, 0, stream>>>(y1f, n1_w, n1_b, nullptr, x1_bf, 1);
    // 7. kv2 = x2 @ kv2_w^T (bf16)
    gemm64<<<dim3(6, 128), 256, 0, stream>>>(x2_bf, wkv2, nullptr, nullptr,
                                             nullptr, kv2, B * N, C, C, 0);
    // 8. kv1 = x1 @ kv1_w^T (bf16)
    gemm64<<<dim3(6, 16), 256, 0, stream>>>(x1_bf, wkv1, nullptr, nullptr,
                                            nullptr, kv1, 1024, C, C, 0);
    // 9/10. vmod = v + dwconv3(v), then transpose -> vt
    {
        int total2 = B * N * 192;
        dwconv_kernel<<<(total2 + 255) / 256, 256, 0, stream>>>(kv2 + 192, lc2_w, lc2_b, vmod2,
                                                                16, 16, 16, N, total2);
        int total1 = B * N1 * 192;
        dwconv_kernel<<<(total1 + 255) / 256, 256, 0, stream>>>(kv1 + 192, lc1_w, lc1_b, vmod1,
                                                                8, 8, 8, N1, total1);
        transpose_kernel<<<dim3(64, 3, 2), 256, 0, stream>>>(vmod2, vt2, 4096);
        transpose_kernel<<<dim3(8, 3, 2), 256, 0, stream>>>(vmod1, vt1, 512);
    }
    // 11. attention: 32 q/block, wave-split-K
    attn_mfma4<<<dim3(N / 32, 8, B), 256, 0, stream>>>(qbB, kv1, kv2, vt1, vt2, Obuf);
    // 13. xres = x + O @ proj_w^T + proj_b (f32)
    gemm64<<<dim3(6, 128), 256, 0, stream>>>(Obuf, wproj, proj_b, x,
                                             xres, nullptr, B * N, C, C, 0);
    // 14. xm = LN(xres) -> bf16
    ln_kernel<<<B * N, 128, 0, stream>>>(xres, ln2_w, ln2_b, nullptr, xm_bf, 0);
    // 15. hid = gelu(xm @ fc1^T + b) (bf16)
    mfma_gemm<<<dim3(12, 64), 256, 0, stream>>>(xm_bf, wfc1, fc1_b, nullptr,
                                                nullptr, hid, B * N, HID, C, 1);
    // 16. out = xres + hid @ fc2^T + b (f32 -> d_out)
    gemm64<<<dim3(6, 128), 256, 0, stream>>>(hid, wfc2, fc2_b, xres,
                                             out, nullptr, B * N, C, HID, 0);
}

// Round 10
// 350.888 us; speedup vs baseline: 12.7745x; 1.0009x over previous
//
#include <hip/hip_runtime.h>

typedef unsigned short ushort_t;
typedef unsigned int uint_t;
typedef __bf16 bf16_t;
typedef __bf16 bf16x8 __attribute__((ext_vector_type(8)));
typedef float f32x4 __attribute__((ext_vector_type(4)));

// ---------- helpers ----------
__device__ __forceinline__ float b2f(ushort_t u) {
    union { uint_t i; float f; } v; v.i = ((uint_t)u) << 16; return v.f;
}
__device__ __forceinline__ ushort_t f2b(float f) {
    union { float f; uint_t i; } v; v.f = f;
    uint_t r = v.i + 0x7fffu + ((v.i >> 16) & 1u);
    return (ushort_t)(r >> 16);
}
__device__ __forceinline__ float gelu_exact(float x) {
    return 0.5f * x * (1.0f + erff(x * 0.70710678118654752f));
}

// ---------- all weight conversions in ONE launch ----------
__global__ void prep_weights(const float* __restrict__ q_w, const float* __restrict__ sr2_w,
                             const float* __restrict__ kv1_w, const float* __restrict__ kv2_w,
                             const float* __restrict__ proj_w, const float* __restrict__ fc1_w,
                             const float* __restrict__ fc2_w, const float* __restrict__ sr1_w,
                             ushort_t* __restrict__ dst) {
    int gid = blockIdx.x * 256 + threadIdx.x;
    int i = gid;
    if (i < 147456) { dst[gid] = f2b(q_w[i]); return; }
    i -= 147456;
    if (i < 147456) { dst[gid] = f2b(sr2_w[i]); return; }
    i -= 147456;
    if (i < 147456) { dst[gid] = f2b(kv1_w[i]); return; }
    i -= 147456;
    if (i < 147456) { dst[gid] = f2b(kv2_w[i]); return; }
    i -= 147456;
    if (i < 147456) { dst[gid] = f2b(proj_w[i]); return; }
    i -= 147456;
    if (i < 589824) { dst[gid] = f2b(fc1_w[i]); return; }
    i -= 589824;
    if (i < 589824) { dst[gid] = f2b(fc2_w[i]); return; }
    i -= 589824;
    if (i < 1179648) {
        int co = i / 3072, r = i % 3072, kk = r / 384, ci = r % 384;
        dst[gid] = f2b(sr1_w[((size_t)co * 384 + ci) * 8 + kk]);
    }
}

// ---------- im2col for sr1 ----------
__global__ void im2col_kernel(const ushort_t* __restrict__ xa, ushort_t* __restrict__ A1) {
    int gid = blockIdx.x * 256 + threadIdx.x;
    if (gid >= 1024 * 3072) return;
    int m = gid / 3072, r = gid % 3072, kk = r / 384, ci = r % 384;
    int b = m >> 9, n1 = m & 511;
    int ho = n1 >> 6, wo = (n1 >> 3) & 7, dz = n1 & 7;
    int n = ((2 * ho + ((kk >> 2) & 1)) << 8) + ((2 * wo + ((kk >> 1) & 1)) << 4) + (2 * dz + (kk & 1));
    A1[gid] = xa[((size_t)b * 4096 + n) * 384 + ci];
}

// ---------- LayerNorm (+ optional GELU); C = 384 ----------
__global__ __launch_bounds__(128) void ln_kernel(const float* __restrict__ in,
                                                 const float* __restrict__ w,
                                                 const float* __restrict__ b,
                                                 float* __restrict__ outf,
                                                 ushort_t* __restrict__ outb, int act) {
    const int C = 384;
    int row = blockIdx.x, tid = threadIdx.x;
    size_t base = (size_t)row * C;
    float x[3], s = 0.f, s2 = 0.f;
#pragma unroll
    for (int i = 0; i < 3; i++) {
        int c = tid + i * 128;
        float v = in[base + c];
        x[i] = v; s += v; s2 += v * v;
    }
    for (int off = 32; off; off >>= 1) { s += __shfl_down(s, off); s2 += __shfl_down(s2, off); }
    __shared__ float sc[4];
    int lane = tid & 63, wid = tid >> 6;
    if (lane == 0) { sc[wid] = s; sc[wid + 2] = s2; }
    __syncthreads();
    float ts = sc[0] + sc[1], ts2 = sc[2] + sc[3];
    float mean = ts / C;
    float var = ts2 / C - mean * mean;
    float rstd = rsqrtf(var + 1e-5f);
#pragma unroll
    for (int i = 0; i < 3; i++) {
        int c = tid + i * 128;
        float v = (x[i] - mean) * rstd * w[c] + b[c];
        if (act) v = gelu_exact(v);
        if (outf) outf[base + c] = v;
        if (outb) outb[base + c] = f2b(v);
    }
}

// ---------- MFMA GEMM 128x128, BK=32 (used for fc1) ----------
__global__ __launch_bounds__(256) void mfma_gemm(const ushort_t* __restrict__ A,
                                                 const ushort_t* __restrict__ W,
                                                 const float* __restrict__ bias,
                                                 const float* __restrict__ res,
                                                 float* __restrict__ outf,
                                                 ushort_t* __restrict__ outb,
                                                 int M, int N, int K, int act) {
    __shared__ bf16_t Asl[128][40];
    __shared__ bf16_t Wsl[128][40];
    int tid = threadIdx.x;
    int wave = tid >> 6, lane = tid & 63, g = lane >> 4, c = lane & 15;
    int wm = wave >> 1, wn = wave & 1;
    int m0 = blockIdx.y * 128, n0 = blockIdx.x * 128;
    int srow = tid >> 1, sseg = tid & 1;

    f32x4 acc[4][4];
#pragma unroll
    for (int i = 0; i < 4; i++)
#pragma unroll
        for (int j = 0; j < 4; j++) acc[i][j] = f32x4{0.f, 0.f, 0.f, 0.f};

    for (int k0 = 0; k0 < K; k0 += 32) {
        const ushort_t* As = A + (size_t)(m0 + srow) * K + k0 + sseg * 16;
        const ushort_t* Ws = W + (size_t)(n0 + srow) * K + k0 + sseg * 16;
        uint4 av0 = *(const uint4*)As, av1 = *(const uint4*)(As + 8);
        uint4 wv0 = *(const uint4*)Ws, wv1 = *(const uint4*)(Ws + 8);
        __syncthreads();
        *(uint4*)&Asl[srow][sseg * 16] = av0;
        *(uint4*)&Asl[srow][sseg * 16 + 8] = av1;
        *(uint4*)&Wsl[srow][sseg * 16] = wv0;
        *(uint4*)&Wsl[srow][sseg * 16 + 8] = wv1;
        __syncthreads();
        bf16x8 af[4], bf[4];
#pragma unroll
        for (int fi = 0; fi < 4; fi++) af[fi] = *(bf16x8*)&Asl[wm * 64 + fi * 16 + c][g * 8];
#pragma unroll
        for (int fj = 0; fj < 4; fj++) bf[fj] = *(bf16x8*)&Wsl[wn * 64 + fj * 16 + c][g * 8];
#pragma unroll
        for (int fi = 0; fi < 4; fi++)
#pragma unroll
            for (int fj = 0; fj < 4; fj++)
                acc[fi][fj] = __builtin_amdgcn_mfma_f32_16x16x32_bf16(af[fi], bf[fj], acc[fi][fj], 0, 0, 0);
    }

#pragma unroll
    for (int fi = 0; fi < 4; fi++) {
#pragma unroll
        for (int fj = 0; fj < 4; fj++) {
            int n = n0 + wn * 64 + fj * 16 + c;
            float bv = bias ? bias[n] : 0.f;
#pragma unroll
            for (int i = 0; i < 4; i++) {
                int m = m0 + wm * 64 + fi * 16 + 4 * g + i;
                float v = acc[fi][fj][i] + bv;
                if (act == 1) v = gelu_exact(v);
                size_t idx = (size_t)m * N + n;
                if (res) v += res[idx];
                if (outf) outf[idx] = v;
                if (outb) outb[idx] = f2b(v);
            }
        }
    }
}

// ---------- MFMA GEMM 64x64, BK=64 (+output scale for Q folding) ----------
__global__ __launch_bounds__(256) void gemm64(const ushort_t* __restrict__ A,
                                              const ushort_t* __restrict__ W,
                                              const float* __restrict__ bias,
                                              const float* __restrict__ res,
                                              float* __restrict__ outf,
                                              ushort_t* __restrict__ outb,
                                              int M, int N, int K, int act, float oscale) {
    __shared__ bf16_t Asl[64][72];
    __shared__ bf16_t Wsl[64][72];
    int tid = threadIdx.x;
    int wave = tid >> 6, lane = tid & 63, g = lane >> 4, c = lane & 15;
    int wm = wave >> 1, wn = wave & 1;
    int m0 = blockIdx.y * 64, n0 = blockIdx.x * 64;
    int srow = tid >> 2, sseg = tid & 3;

    f32x4 acc[2][2];
#pragma unroll
    for (int i = 0; i < 2; i++)
#pragma unroll
        for (int j = 0; j < 2; j++) acc[i][j] = f32x4{0.f, 0.f, 0.f, 0.f};

    for (int k0 = 0; k0 < K; k0 += 64) {
        const ushort_t* As = A + (size_t)(m0 + srow) * K + k0 + sseg * 16;
        const ushort_t* Ws = W + (size_t)(n0 + srow) * K + k0 + sseg * 16;
        uint4 av0 = *(const uint4*)As, av1 = *(const uint4*)(As + 8);
        uint4 wv0 = *(const uint4*)Ws, wv1 = *(const uint4*)(Ws + 8);
        __syncthreads();
        *(uint4*)&Asl[srow][sseg * 16] = av0;
        *(uint4*)&Asl[srow][sseg * 16 + 8] = av1;
        *(uint4*)&Wsl[srow][sseg * 16] = wv0;
        *(uint4*)&Wsl[srow][sseg * 16 + 8] = wv1;
        __syncthreads();
#pragma unroll
        for (int kk = 0; kk < 2; kk++) {
            bf16x8 af[2], bf[2];
#pragma unroll
            for (int fi = 0; fi < 2; fi++) af[fi] = *(bf16x8*)&Asl[wm * 32 + fi * 16 + c][kk * 32 + g * 8];
#pragma unroll
            for (int fj = 0; fj < 2; fj++) bf[fj] = *(bf16x8*)&Wsl[wn * 32 + fj * 16 + c][kk * 32 + g * 8];
#pragma unroll
            for (int fi = 0; fi < 2; fi++)
#pragma unroll
                for (int fj = 0; fj < 2; fj++)
                    acc[fi][fj] = __builtin_amdgcn_mfma_f32_16x16x32_bf16(af[fi], bf[fj], acc[fi][fj], 0, 0, 0);
        }
    }

#pragma unroll
    for (int fi = 0; fi < 2; fi++) {
#pragma unroll
        for (int fj = 0; fj < 2; fj++) {
            int n = n0 + wn * 32 + fj * 16 + c;
            float bv = bias ? bias[n] : 0.f;
#pragma unroll
            for (int i = 0; i < 4; i++) {
                int m = m0 + wm * 32 + fi * 16 + 4 * g + i;
                float v = (acc[fi][fj][i] + bv) * oscale;
                if (act == 1) v = gelu_exact(v);
                size_t idx = (size_t)m * N + n;
                if (res) v += res[idx];
                if (outf) outf[idx] = v;
                if (outb) outb[idx] = f2b(v);
            }
        }
    }
}

// ---------- depthwise 3x3x3 SAME residual conv on V ----------
__global__ void dwconv_kernel(const ushort_t* __restrict__ vin,
                              const float* __restrict__ wt,
                              const float* __restrict__ bias,
                              ushort_t* __restrict__ vout,
                              int Hs, int Wsz, int Ds, int S, int total) {
    int gid = blockIdx.x * 256 + threadIdx.x;
    if (gid >= total) return;
    int c2 = gid % 192;
    int r = gid / 192;
    int n = r % S;
    int b = r / S;
    int dz = n % Ds, wy = (n / Ds) % Wsz, hx = n / (Wsz * Ds);
    float center = b2f(vin[(size_t)(b * S + n) * 384 + c2]);
    float acc = bias[c2];
    for (int kh = -1; kh <= 1; kh++) {
        int h2 = hx + kh; if (h2 < 0 || h2 >= Hs) continue;
        for (int kw = -1; kw <= 1; kw++) {
            int w2 = wy + kw; if (w2 < 0 || w2 >= Wsz) continue;
            for (int kd = -1; kd <= 1; kd++) {
                int d2 = dz + kd; if (d2 < 0 || d2 >= Ds) continue;
                int nn = (h2 * Wsz + w2) * Ds + d2;
                acc += b2f(vin[(size_t)(b * S + nn) * 384 + c2]) *
                       wt[c2 * 27 + (kh + 1) * 9 + (kw + 1) * 3 + (kd + 1)];
            }
        }
    }
    vout[(size_t)(b * S + n) * 192 + c2] = f2b(center + acc);
}

// ---------- transpose vmod [b][S][192] -> vt [b][192][S] ----------
__global__ __launch_bounds__(256) void transpose_kernel(const ushort_t* __restrict__ src,
                                                        ushort_t* __restrict__ dst, int S) {
    __shared__ ushort_t t_lds[64][65];
    int n0 = blockIdx.x * 64, c0 = blockIdx.y * 64, b = blockIdx.z;
    int tid = threadIdx.x;
#pragma unroll
    for (int i = 0; i < 16; i++) {
        int idx = tid + i * 256;
        int r = idx >> 6, cc = idx & 63;
        t_lds[r][cc] = src[((size_t)b * S + n0 + r) * 192 + c0 + cc];
    }
    __syncthreads();
#pragma unroll
    for (int i = 0; i < 16; i++) {
        int idx = tid + i * 256;
        int r = idx >> 6, cc = idx & 63;
        dst[((size_t)b * 192 + c0 + r) * S + n0 + cc] = t_lds[cc][r];
    }
}

// ---------- MFMA flash attention v5: no-max exp2 softmax (scores pre-scaled in Q) ----------
// grid (N/32, 8, 2). hl 0..3: NK=512; hl 4..7: NK=4096. Wave w handles keys [w*NK/4, ...).
// Q was scaled by 48^-0.5 * log2(e) at projection; p = exp2(q'·k) = exp(s_true); m == 0.
__global__ __launch_bounds__(256, 4) void attn_mfma5(
    const ushort_t* __restrict__ qbuf,
    const ushort_t* __restrict__ kv1,
    const ushort_t* __restrict__ kv2,
    const ushort_t* __restrict__ vt1,
    const ushort_t* __restrict__ vt2,
    ushort_t* __restrict__ obuf)
{
    __shared__ __align__(16) char lds_raw[18432];
    bf16_t (*P)[32][72] = (bf16_t (*)[32][72])lds_raw;   // per-wave P tile
    float (*CF)[64][14] = (float (*)[64][14])lds_raw;    // combine buffer (after k-loop)

    const int N = 4096;
    int tid = threadIdx.x;
    int q0 = blockIdx.x * 32, hl = 7 - blockIdx.y, b = blockIdx.z;
    int wave = tid >> 6, lane = tid & 63, g = lane >> 4, c = lane & 15;
    int br2 = hl >> 2;
    int NK = br2 ? 4096 : 512;
    const ushort_t* kbuf = br2 ? kv2 : kv1;
    const ushort_t* vtb  = br2 ? vt2 : vt1;
    int hloc = hl & 3;
    int NKc = NK >> 2;
    int kb0 = wave * NKc;
    int nkt = NKc >> 6;

    union { uint4 u; bf16x8 v; } zz; zz.u = uint4{0u, 0u, 0u, 0u};
    const bf16x8 zero8 = zz.v;

    // ---- Q B-fragments in registers (2 q-groups of 16), zero-pad k=48..63 ----
    bf16x8 bq0[2], bq1[2];
#pragma unroll
    for (int qg = 0; qg < 2; qg++) {
        const ushort_t* qrowp = qbuf + ((size_t)b * N + q0 + qg * 16 + c) * 384 + hl * 48;
        bq0[qg] = *(const bf16x8*)(qrowp + g * 8);
        bq1[qg] = (g < 2) ? *(const bf16x8*)(qrowp + 32 + g * 8) : zero8;
    }

    f32x4 of[3][2];
#pragma unroll
    for (int dt = 0; dt < 3; dt++)
#pragma unroll
        for (int qg = 0; qg < 2; qg++) of[dt][qg] = f32x4{0.f, 0.f, 0.f, 0.f};
    float l_acc[2] = {0.f, 0.f};

    const ushort_t* kp = kbuf + ((size_t)b * NK + kb0 + c) * 384 + hloc * 48;
    const ushort_t* vp = vtb + ((size_t)b * 192 + hloc * 48 + c) * NK + kb0;

    for (int kt = 0; kt < nkt; kt++) {
        // ---- S^T = K Q^T ----
        f32x4 sf[4][2];
#pragma unroll
        for (int t = 0; t < 4; t++)
#pragma unroll
            for (int qg = 0; qg < 2; qg++) sf[t][qg] = f32x4{0.f, 0.f, 0.f, 0.f};
#pragma unroll
        for (int t = 0; t < 4; t++) {
            const ushort_t* kr = kp + (size_t)(kt * 64 + 16 * t) * 384;
            bf16x8 ak0 = *(const bf16x8*)(kr + g * 8);
            bf16x8 ak1 = (g < 2) ? *(const bf16x8*)(kr + 32 + g * 8) : zero8;
#pragma unroll
            for (int qg = 0; qg < 2; qg++) {
                sf[t][qg] = __builtin_amdgcn_mfma_f32_16x16x32_bf16(ak0, bq0[qg], sf[t][qg], 0, 0, 0);
                sf[t][qg] = __builtin_amdgcn_mfma_f32_16x16x32_bf16(ak1, bq1[qg], sf[t][qg], 0, 0, 0);
            }
        }

        // ---- p = exp2(s'); accumulate l; pack to P (no max, no rescale) ----
#pragma unroll
        for (int qg = 0; qg < 2; qg++) {
#pragma unroll
            for (int t = 0; t < 4; t++) {
                union { ushort4 v; bf16_t h[4]; } pk;
#pragma unroll
                for (int i = 0; i < 4; i++) {
                    float p = exp2f(sf[t][qg][i]);
                    l_acc[qg] += p;
                    pk.h[i] = (bf16_t)p;
                }
                *(ushort4*)&P[wave][qg * 16 + c][16 * t + 4 * g] = pk.v;
            }
        }

        // wave-local P write->read ordering fence
        asm volatile("s_waitcnt lgkmcnt(0)" ::: "memory");

        // ---- O^T += VT P^T ----
        bf16x8 pb0[2], pb1[2];
#pragma unroll
        for (int qg = 0; qg < 2; qg++) {
            pb0[qg] = *(bf16x8*)&P[wave][qg * 16 + c][g * 8];
            pb1[qg] = *(bf16x8*)&P[wave][qg * 16 + c][32 + g * 8];
        }
#pragma unroll
        for (int dt = 0; dt < 3; dt++) {
            const ushort_t* vr = vp + (size_t)(16 * dt) * NK + kt * 64;
            bf16x8 av0 = *(const bf16x8*)(vr + g * 8);
            bf16x8 av1 = *(const bf16x8*)(vr + 32 + g * 8);
#pragma unroll
            for (int qg = 0; qg < 2; qg++) {
                of[dt][qg] = __builtin_amdgcn_mfma_f32_16x16x32_bf16(av0, pb0[qg], of[dt][qg], 0, 0, 0);
                of[dt][qg] = __builtin_amdgcn_mfma_f32_16x16x32_bf16(av1, pb1[qg], of[dt][qg], 0, 0, 0);
            }
        }
    }

    // ---- one-shot l reduce across g-groups (lane's 16-key partials -> full chunk sum) ----
#pragma unroll
    for (int qg = 0; qg < 2; qg++) {
        l_acc[qg] += __shfl_xor(l_acc[qg], 16);
        l_acc[qg] += __shfl_xor(l_acc[qg], 32);
    }

    // ---- cross-wave combine (plain sums; waves hold disjoint key chunks) ----
#pragma unroll
    for (int qg = 0; qg < 2; qg++) {
        __syncthreads();
        float* cfp = &CF[wave][lane][0];
#pragma unroll
        for (int dt = 0; dt < 3; dt++)
#pragma unroll
            for (int i = 0; i < 4; i++) cfp[dt * 4 + i] = of[dt][qg][i];
        cfp[12] = l_acc[qg];
        __syncthreads();
        if (wave == 0) {
            float lsum = 0.f;
            float oc[12];
#pragma unroll
            for (int j = 0; j < 12; j++) oc[j] = 0.f;
#pragma unroll
            for (int w = 0; w < 4; w++) {
                lsum += CF[w][lane][12];
#pragma unroll
                for (int j = 0; j < 12; j++) oc[j] += CF[w][lane][j];
            }
            float rl = 1.f / lsum;
            int qrow = q0 + qg * 16 + c;
#pragma unroll
            for (int dt = 0; dt < 3; dt++) {
                union { ushort4 v; bf16_t h[4]; } pk;
#pragma unroll
                for (int i = 0; i < 4; i++) pk.h[i] = (bf16_t)(oc[dt * 4 + i] * rl);
                *(ushort4*)&obuf[((size_t)b * N + qrow) * 384 + hl * 48 + 16 * dt + 4 * g] = pk.v;
            }
        }
    }
}

// ---------- host ----------
extern "C" void kernel_launch(void* const* d_in, const int* in_sizes, int n_in,
                              void* d_out, int out_size, void* d_ws, size_t ws_size,
                              hipStream_t stream) {
    const int B = 2, N = 4096, C = 384, N1 = 512, HID = 1536;
    const float* x      = (const float*)d_in[0];
    const float* ln1_w  = (const float*)d_in[1];
    const float* ln1_b  = (const float*)d_in[2];
    const float* q_w    = (const float*)d_in[3];
    const float* sr1_w  = (const float*)d_in[4];
    const float* sr1_b  = (const float*)d_in[5];
    const float* n1_w   = (const float*)d_in[6];
    const float* n1_b   = (const float*)d_in[7];
    const float* sr2_w  = (const float*)d_in[8];
    const float* sr2_b  = (const float*)d_in[9];
    const float* n2_w   = (const float*)d_in[10];
    const float* n2_b   = (const float*)d_in[11];
    const float* kv1_w  = (const float*)d_in[12];
    const float* kv2_w  = (const float*)d_in[13];
    const float* lc1_w  = (const float*)d_in[14];
    const float* lc1_b  = (const float*)d_in[15];
    const float* lc2_w  = (const float*)d_in[16];
    const float* lc2_b  = (const float*)d_in[17];
    const float* proj_w = (const float*)d_in[18];
    const float* proj_b = (const float*)d_in[19];
    const float* ln2_w  = (const float*)d_in[20];
    const float* ln2_b  = (const float*)d_in[21];
    const float* fc1_w  = (const float*)d_in[22];
    const float* fc1_b  = (const float*)d_in[23];
    const float* fc2_w  = (const float*)d_in[24];
    const float* fc2_b  = (const float*)d_in[25];
    float* out = (float*)d_out;

    char* ws = (char*)d_ws;
    ushort_t* wbase = (ushort_t*)ws;
    ushort_t* wq   = wbase;
    ushort_t* wsr2 = wbase + 147456;
    ushort_t* wkv1 = wbase + 294912;
    ushort_t* wkv2 = wbase + 442368;
    ushort_t* wproj= wbase + 589824;
    ushort_t* wfc1 = wbase + 737280;
    ushort_t* wfc2 = wbase + 1327104;
    ushort_t* wsr1 = wbase + 1916928;
    ushort_t* xa_bf = (ushort_t*)(ws + 6193152);
    ushort_t* qbB   = (ushort_t*)(ws + 12484608);
    ushort_t* x2_bf = (ushort_t*)(ws + 18776064);
    ushort_t* kv2   = (ushort_t*)(ws + 25067520);
    ushort_t* vmod2 = (ushort_t*)(ws + 31358976);
    ushort_t* kv1   = (ushort_t*)(ws + 34504704);
    ushort_t* vmod1 = (ushort_t*)(ws + 35291136);
    ushort_t* x1_bf = (ushort_t*)(ws + 35684352);
    float*    y2f   = (float*)(ws + 36470784);
    float*    y1f   = (float*)(ws + 49053696);
    ushort_t* A1    = (ushort_t*)(ws + 50626560);
    ushort_t* hid   = (ushort_t*)(ws + 56918016);
    ushort_t* vt2   = (ushort_t*)(ws + 82083840);
    ushort_t* vt1   = (ushort_t*)(ws + 85229568);
    ushort_t* Obuf  = xa_bf;
    float*    xres  = y2f;
    ushort_t* xm_bf = A1;

    // scale * log2(e): folded into Q so attention uses exp2 directly
    const float QSCALE = 0.14433756729740643f * 1.4426950408889634f;

    // 0. weights
    prep_weights<<<(3096576 + 255) / 256, 256, 0, stream>>>(q_w, sr2_w, kv1_w, kv2_w,
                                                            proj_w, fc1_w, fc2_w, sr1_w, wbase);
    // 1. xa = LN(x) -> bf16
    ln_kernel<<<B * N, 128, 0, stream>>>(x, ln1_w, ln1_b, nullptr, xa_bf, 0);
    // 2. q = (xa @ q_w^T) * QSCALE (bf16)
    gemm64<<<dim3(6, 128), 256, 0, stream>>>(xa_bf, wq, nullptr, nullptr,
                                             nullptr, qbB, B * N, C, C, 0, QSCALE);
    // 3. y2 = xa @ sr2_w^T + b (f32)
    gemm64<<<dim3(6, 128), 256, 0, stream>>>(xa_bf, wsr2, sr2_b, nullptr,
                                             y2f, nullptr, B * N, C, C, 0, 1.f);
    // 4. x2 = gelu(LN(y2)) -> bf16
    ln_kernel<<<B * N, 128, 0, stream>>>(y2f, n2_w, n2_b, nullptr, x2_bf, 1);
    // 5. im2col + sr1 GEMM
    im2col_kernel<<<(1024 * 3072 + 255) / 256, 256, 0, stream>>>(xa_bf, A1);
    gemm64<<<dim3(6, 16), 256, 0, stream>>>(A1, wsr1, sr1_b, nullptr,
                                            y1f, nullptr, 1024, C, 3072, 0, 1.f);
    // 6. x1 = gelu(LN(y1)) -> bf16
    ln_kernel<<<B * N1, 128, 0, stream>>>(y1f, n1_w, n1_b, nullptr, x1_bf, 1);
    // 7. kv2 = x2 @ kv2_w^T (bf16)
    gemm64<<<dim3(6, 128), 256, 0, stream>>>(x2_bf, wkv2, nullptr, nullptr,
                                             nullptr, kv2, B * N, C, C, 0, 1.f);
    // 8. kv1 = x1 @ kv1_w^T (bf16)
    gemm64<<<dim3(6, 16), 256, 0, stream>>>(x1_bf, wkv1, nullptr, nullptr,
                                            nullptr, kv1, 1024, C, C, 0, 1.f);
    // 9/10. vmod = v + dwconv3(v), then transpose -> vt
    {
        int total2 = B * N * 192;
        dwconv_kernel<<<(total2 + 255) / 256, 256, 0, stream>>>(kv2 + 192, lc2_w, lc2_b, vmod2,
                                                                16, 16, 16, N, total2);
        int total1 = B * N1 * 192;
        dwconv_kernel<<<(total1 + 255) / 256, 256, 0, stream>>>(kv1 + 192, lc1_w, lc1_b, vmod1,
                                                                8, 8, 8, N1, total1);
        transpose_kernel<<<dim3(64, 3, 2), 256, 0, stream>>>(vmod2, vt2, 4096);
        transpose_kernel<<<dim3(8, 3, 2), 256, 0, stream>>>(vmod1, vt1, 512);
    }
    // 11. attention v5 (no-max exp2)
    attn_mfma5<<<dim3(N / 32, 8, B), 256, 0, stream>>>(qbB, kv1, kv2, vt1, vt2, Obuf);
    // 13. xres = x + O @ proj_w^T + proj_b (f32)
    gemm64<<<dim3(6, 128), 256, 0, stream>>>(Obuf, wproj, proj_b, x,
                                             xres, nullptr, B * N, C, C, 0, 1.f);
    // 14. xm = LN(xres) -> bf16
    ln_kernel<<<B * N, 128, 0, stream>>>(xres, ln2_w, ln2_b, nullptr, xm_bf, 0);
    // 15. hid = gelu(xm @ fc1^T + b) (bf16)
    mfma_gemm<<<dim3(12, 64), 256, 0, stream>>>(xm_bf, wfc1, fc1_b, nullptr,
                                                nullptr, hid, B * N, HID, C, 1);
    // 16. out = xres + hid @ fc2^T + b (f32 -> d_out)
    gemm64<<<dim3(6, 128), 256, 0, stream>>>(hid, wfc2, fc2_b, xres,
                                             out, nullptr, B * N, C, HID, 0, 1.f);
}